// Round 4
// baseline (291.424 us; speedup 1.0000x reference)
//
#include <hip/hip_runtime.h>
#include <hip/hip_bf16.h>

#define NN 64
#define BATCH 512
#define SP 60
#define SG 180
#define SEX 10
#define CATD 80
#define NA 5
#define NR 7
#define OO 8
#define II 8

typedef unsigned long long u64;
typedef unsigned short u16;
typedef unsigned int u32;
typedef unsigned char u8;

// ---- workspace layout (float offsets) ----
#define OFF_Z     0
#define OFF_DZ    327680
#define OFF_HAS   655360
#define OFF_WIHF  688128
#define OFF_WHHF  698928
#define OFF_BIHF  709728
#define OFF_BHHF  709908
#define OFF_WIHB  710088
#define OFF_WHHB  720888
#define OFF_BIHB  731688
#define OFF_BHHB  731868
#define OFF_WF    732048
#define OFF_BF    736848
#define OFF_WB    736908
#define OFF_BB    741708
#define OFF_WA    741768
#define OFF_BA    742368
#define OFF_WC    742373
#define OFF_BC    742493
#define OFF_WU    742494
#define OFF_BU    743334
#define CONV_TOTAL 743341
#define OFF_FLAG  743342
#define OFF_RHOF  743344
#define OFF_RHOB  (OFF_RHOF + 1966080)
#define OFF_ALF   (OFF_RHOB + 1966080)
#define OFF_ALB   (OFF_ALF + 30720)
#define OUT_TOTAL 232448

typedef _Float16 f16;
typedef _Float16 half2_t __attribute__((ext_vector_type(2)));
typedef _Float16 f16x8 __attribute__((ext_vector_type(8)));
typedef float f32x4 __attribute__((ext_vector_type(4)));

__device__ __forceinline__ float us2f(u16 v){
  return __uint_as_float(((u32)v) << 16);
}
__device__ __forceinline__ u16 f2bf(float f){
  __hip_bfloat16 h = __float2bfloat16(f);
  return *reinterpret_cast<u16*>(&h);
}
__device__ __forceinline__ float rcp_(float x){ return __builtin_amdgcn_rcpf(x); }
__device__ __forceinline__ float sigm(float x){
  return rcp_(1.f + __expf(-x));
}
__device__ __forceinline__ float tanh_(float x){
  float e = __expf(2.f*fabsf(x));
  float t = 1.f - 2.f*rcp_(e + 1.f);
  return copysignf(t, x);
}
__device__ __forceinline__ u32 pack2(float a, float b){
  half2_t h; h[0] = (f16)a; h[1] = (f16)b;
  return __builtin_bit_cast(u32, h);
}
__device__ __forceinline__ float fdot2_(u32 a, u32 b, float c){
  return __builtin_amdgcn_fdot2(__builtin_bit_cast(half2_t, a),
                                __builtin_bit_cast(half2_t, b), c, false);
}
__device__ __forceinline__ f16x8 bc16(uint4 v){ return __builtin_bit_cast(f16x8, v); }
__device__ __forceinline__ f32x4 mfma16(f16x8 a, f16x8 b, f32x4 c){
  return __builtin_amdgcn_mfma_f32_16x16x32_f16(a, b, c, 0, 0, 0);
}

// has is exactly {0,1}. f32 words: only 0x00000000 / 0x3F800000.
// bf16-pair words: 0x3F803F80 == (1.0,1.0) appears w.p. ~0.81 per pair.
__device__ __forceinline__ int detect_bf16(const u32* w){
  int f = 0;
  for (int i=0;i<256;i++) f |= (w[i] == 0x3F803F80u) ? 1 : 0;
  return f;
}

__global__ __launch_bounds__(256) void conv_in(
  const void* z, const void* dz, const void* has,
  const void* WihF, const void* WhhF, const void* bihF, const void* bhhF,
  const void* WihB, const void* WhhB, const void* bihB, const void* bhhB,
  const void* Wf_, const void* bf_, const void* Wb_, const void* bb_,
  const void* Wa, const void* ba, const void* Wc, const void* bc,
  const void* Wu, const void* bu, float* ws)
{
  const int isbf = detect_bf16((const u32*)has);
  if (blockIdx.x == 0 && threadIdx.x == 0) ws[OFF_FLAG] = (float)isbf;
  int idx = blockIdx.x*256 + threadIdx.x;
  if (idx >= CONV_TOTAL) return;
  const void* src; int loc;
  if      (idx < OFF_DZ  ){ src=z;    loc=idx-OFF_Z;    }
  else if (idx < OFF_HAS ){ src=dz;   loc=idx-OFF_DZ;   }
  else if (idx < OFF_WIHF){ src=has;  loc=idx-OFF_HAS;  }
  else if (idx < OFF_WHHF){ src=WihF; loc=idx-OFF_WIHF; }
  else if (idx < OFF_BIHF){ src=WhhF; loc=idx-OFF_WHHF; }
  else if (idx < OFF_BHHF){ src=bihF; loc=idx-OFF_BIHF; }
  else if (idx < OFF_WIHB){ src=bhhF; loc=idx-OFF_BHHF; }
  else if (idx < OFF_WHHB){ src=WihB; loc=idx-OFF_WIHB; }
  else if (idx < OFF_BIHB){ src=WhhB; loc=idx-OFF_WHHB; }
  else if (idx < OFF_BHHB){ src=bihB; loc=idx-OFF_BIHB; }
  else if (idx < OFF_WF  ){ src=bhhB; loc=idx-OFF_BHHB; }
  else if (idx < OFF_BF  ){ src=Wf_;  loc=idx-OFF_WF;   }
  else if (idx < OFF_WB  ){ src=bf_;  loc=idx-OFF_BF;   }
  else if (idx < OFF_BB  ){ src=Wb_;  loc=idx-OFF_WB;   }
  else if (idx < OFF_WA  ){ src=bb_;  loc=idx-OFF_BB;   }
  else if (idx < OFF_BA  ){ src=Wa;   loc=idx-OFF_WA;   }
  else if (idx < OFF_WC  ){ src=ba;   loc=idx-OFF_BA;   }
  else if (idx < OFF_BC  ){ src=Wc;   loc=idx-OFF_WC;   }
  else if (idx < OFF_WU  ){ src=bc;   loc=idx-OFF_BC;   }
  else if (idx < OFF_BU  ){ src=Wu;   loc=idx-OFF_WU;   }
  else                    { src=bu;   loc=idx-OFF_BU;   }
  float v = isbf ? us2f(((const u16*)src)[loc]) : ((const float*)src)[loc];
  ws[idx] = v;
}

// r15: 2-barrier step. vs r14 (4 barriers + wave0-serial phase1b):
//  - barrier B dropped: group-0 Bh fragments preloaded pre-P (P separates
//    reads from writes); group-1 rows are disjoint -> no barrier needed
//  - 6 of 11 MFMAs (h-dependent Dr/Dz/Dn halves) hoisted pre-P
//  - barrier A dropped: all 4 waves redundantly combine sPart + tanh and
//    build Br0/Br1 fragments in-register via 16 ds_bpermute (intra-wave);
//    wave0 alone stores rho to global + hist
// Step: [preload+6MFMA+phase1a] -> P -> [combine+bperm+5MFMA+gates] -> C.
__global__ __launch_bounds__(256, 4) void dir_kernel(const int* __restrict__ adj,
                                                     float* __restrict__ ws)
{
  const int tid = threadIdx.x;
  const int w   = tid >> 6;         // wave id (0..3) == row tile mt
  const int u   = tid & 63;         // lane
  const int ml  = u & 15;           // MFMA col (consumer slot)
  const int q   = u >> 4;           // MFMA quad
  const int bid = blockIdx.x;
  const int bwd = bid >> 9;
  const int b   = bid & 511;

  const float* Wih  = ws + (bwd ? OFF_WIHB : OFF_WIHF);
  const float* Whh  = ws + (bwd ? OFF_WHHB : OFF_WHHF);
  const float* bih  = ws + (bwd ? OFF_BIHB : OFF_BIHF);
  const float* bhh  = ws + (bwd ? OFF_BHHB : OFF_BHHF);
  const float* Wcat = ws + (bwd ? OFF_WB   : OFF_WF);
  const float* bcat = ws + (bwd ? OFF_BB   : OFF_BF);
  const float* zc   = ws + OFF_Z;
  const float* dzc  = ws + OFF_DZ;
  const float* hasc = ws + OFF_HAS;
  float* rho   = ws + (bwd ? OFF_RHOB : OFF_RHOF);  // [64][512][60]
  float* alpha = ws + (bwd ? OFF_ALB  : OFF_ALF);   // [512][60]

  __shared__ uint4 sH4[65][9];        // h rows, 144B stride; half63=1.0 (bias ch)
  __shared__ uint4 sRhoHist[8][8];    // tail rho history; half63=1.0
  __shared__ float sZdc[NN][SP];      // precomputed bias + z/dz contribution
  __shared__ float sPart[4][64];      // phase-1 partials per wave
  __shared__ u32 sZp[NN][5];
  __shared__ u32 sDZp[NN][5];
  __shared__ float sHas[NN];
  __shared__ u64 sRowM[NN];
  __shared__ u8 sConsL[NN][64];       // consumer lists (batch-independent)
  __shared__ int sConsCnt[NN];

  #define ROWB(I) ((char*)&sH4[(I)][0])
  const u32 BIASW = 0x3C000000u;      // halves {0, 1.0h}

  // ---- staging ----
  {
    if (tid < 64){
      u64 rowm = 0;
      for (int j=0;j<64;j++) rowm |= ((u64)(adj[tid*64+j]!=0))<<j;
      sRowM[tid] = rowm;
      sHas[tid] = hasc[b*NN + tid];
    }
    for (int idx=tid; idx<65*9; idx+=256){
      uint4 v = {0,0,0,0};
      if (idx % 9 == 7) v.w = BIASW;         // half63 = 1.0
      ((uint4*)sH4)[idx] = v;
    }
    if (tid < 64){ uint4 v={0,0,0,0}; if ((tid&7)==7) v.w = BIASW; ((uint4*)sRhoHist)[tid]=v; }
    for (int idx=tid; idx<NN*5; idx+=256){
      int n2=idx/5, p2=idx%5;
      sZp [n2][p2] = pack2(zc [(size_t)b*NN*SEX + n2*SEX + 2*p2],
                           zc [(size_t)b*NN*SEX + n2*SEX + 2*p2+1]);
      sDZp[n2][p2] = pack2(dzc[(size_t)b*NN*SEX + n2*SEX + 2*p2],
                           dzc[(size_t)b*NN*SEX + n2*SEX + 2*p2+1]);
    }
  }
  __syncthreads();
  if (tid < 64){
    u64 cm = 0;
    if (bwd) for (int i2=0;i2<64;i2++) cm |= ((sRowM[i2]>>tid)&1ULL)<<i2;
    u64 m = bwd ? cm : sRowM[tid];          // consumers of node tid
    int c = 0;
    while (m){ int i2 = (int)__builtin_ctzll(m); m &= m-1; sConsL[tid][c++] = (u8)i2; }
    sConsCnt[tid] = c;
  }
  // zdc precompute: sZdc[t][uu] = bcat[uu] + Wz.z_t + Wdz.dz_t (bias folded).
  // Wave tw handles t = tw, tw+4, ...; weights transient (staging only).
  {
    const int uu = tid & 63;
    const int tw = tid >> 6;
    if (uu < SP){
      u32 wz[10];
      #pragma unroll
      for (int p=0;p<10;p++)
        wz[p] = pack2(Wcat[uu*CATD + 60 + 2*p], Wcat[uu*CATD + 60 + 2*p + 1]);
      const float bb0 = bcat[uu];
      for (int t2=tw; t2<NN; t2+=4){
        float c = bb0;
        #pragma unroll
        for (int p=0;p<5;p++){
          c = fdot2_(wz[p],   sZp [t2][p], c);
          c = fdot2_(wz[5+p], sDZp[t2][p], c);
        }
        sZdc[t2][uu] = c;
      }
    }
  }

  // ---- A fragments (wave w owns mt = w): lane (q,ml) holds
  // A[row=16w+ml][K=32kt+8q+j] ----
  // Ar/Az: K<60 Whh, 64<=K<124 Wih, K==127 bias (bhh+bih).
  // Anh:   K<60 Whh_n, K==63 bias bhh_n.   Ani: K<60 Wih_n, K==63 bias bih_n.
  f16x8 Ar[4], Az[4], Anh[2], Ani[2];
  {
    const int R = 16*w + ml;
    const bool rok = (R < SP);
    #pragma unroll
    for (int kt=0; kt<4; kt++){
      f16x8 vr, vz;
      #pragma unroll
      for (int j=0;j<8;j++){
        const int K = 32*kt + 8*q + j;
        float wr=0.f, wz2=0.f;
        if (rok){
          if (K < SP){ wr = Whh[R*SP+K]; wz2 = Whh[(60+R)*SP+K]; }
          else if (K >= 64 && K < 64+SP){ wr = Wih[R*SP+(K-64)]; wz2 = Wih[(60+R)*SP+(K-64)]; }
          else if (K == 127){ wr = bhh[R]+bih[R]; wz2 = bhh[60+R]+bih[60+R]; }
        }
        vr[j]=(f16)wr; vz[j]=(f16)wz2;
      }
      Ar[kt]=vr; Az[kt]=vz;
    }
    #pragma unroll
    for (int kt=0; kt<2; kt++){
      f16x8 vn, vi;
      #pragma unroll
      for (int j=0;j<8;j++){
        const int K = 32*kt + 8*q + j;
        float wn=0.f, wi=0.f;
        if (rok){
          if (K < SP){ wn = Whh[(120+R)*SP+K]; wi = Wih[(120+R)*SP+K]; }
          else if (K == 63){ wn = bhh[120+R]; wi = bih[120+R]; }
        }
        vn[j]=(f16)wn; vi[j]=(f16)wi;
      }
      Anh[kt]=vn; Ani[kt]=vi;
    }
  }

  // phase-1 h-weights, distributed: wave w owns pairs 8w..8w+7 (wave 3: 6)
  u32 wc[8];
  #pragma unroll
  for (int k=0;k<8;k++){
    const int kk = 8*w + k;
    wc[k] = (kk < 30) ? pack2(Wcat[u*CATD + 2*kk], Wcat[u*CATD + 2*kk + 1]) : 0u;
  }
  __syncthreads();   // lists + zdc + LDS init visible

  // gates: in-register GRU gate math + h read-modify-write for row tile w,
  // consumer ci, slot column ml. Each wave touches only bytes [32w,32w+32)
  // of the row -> no cross-wave overlap.
  auto gates = [&](f32x4 Dr, f32x4 Dz, f32x4 Dn, f32x4 Gn,
                   int ci, bool wr, float bl){
    char* rp = ROWB(ci) + 32*w + 8*q;
    uint2 h2 = *(uint2*)rp;
    half2_t ha = __builtin_bit_cast(half2_t, h2.x);
    half2_t hb = __builtin_bit_cast(half2_t, h2.y);
    float hold[4] = { (float)ha[0], (float)ha[1], (float)hb[0], (float)hb[1] };
    float hw[4];
    #pragma unroll
    for (int reg=0;reg<4;reg++){
      float r_ = sigm(Dr[reg]);
      float zg = sigm(Dz[reg]);
      float nv = tanh_(Gn[reg] + r_*Dn[reg]);
      float hn_ = (1.f - zg)*nv + zg*hold[reg];
      hw[reg] = (bl != 0.f) ? hn_ : hold[reg];   // bl is exactly 0 or 1
    }
    if (wr && !(w==3 && q==3)){
      uint2 o; o.x = pack2(hw[0],hw[1]); o.y = pack2(hw[2],hw[3]);
      *(uint2*)rp = o;
    }
  };

  // full 11-MFMA pass (group 1 + tail)
  auto fullpass = [&](f16x8 Bh0, f16x8 Bh1, f16x8 Br0, f16x8 Br1,
                      f32x4 Gn, int ci, bool wr, float bl){
    f32x4 Dr={0,0,0,0}, Dz={0,0,0,0}, Dn={0,0,0,0};
    Dr = mfma16(Ar[0], Bh0, Dr); Dr = mfma16(Ar[1], Bh1, Dr);
    Dr = mfma16(Ar[2], Br0, Dr); Dr = mfma16(Ar[3], Br1, Dr);
    Dz = mfma16(Az[0], Bh0, Dz); Dz = mfma16(Az[1], Bh1, Dz);
    Dz = mfma16(Az[2], Br0, Dz); Dz = mfma16(Az[3], Br1, Dz);
    Dn = mfma16(Anh[0], Bh0, Dn); Dn = mfma16(Anh[1], Bh1, Dn);
    gates(Dr, Dz, Dn, Gn, ci, wr, bl);
  };

  // ---- 64 pipelined steps, 2 barriers each ----
  int t = bwd ? 63 : 0;
  const int dt = bwd ? -1 : 1;
  for (int s=0; s<64; s++, t+=dt){
    const float blendT = sHas[t];
    const int cnt = sConsCnt[t];
    const bool act = (blendT != 0.f) && (cnt > 0);   // block-uniform

    // pre-P: group-0 Bh preload + h-dependent MFMA halves
    f32x4 Dr={0,0,0,0}, Dz={0,0,0,0}, Dn={0,0,0,0};
    int ci0 = 64;
    if (act){
      ci0 = (ml < cnt) ? (int)sConsL[t][ml] : 64;
      const f16x8 Bh0 = bc16(sH4[ci0][q]);
      const f16x8 Bh1 = bc16(sH4[ci0][4+q]);
      Dr = mfma16(Ar[0], Bh0, Dr); Dr = mfma16(Ar[1], Bh1, Dr);
      Dz = mfma16(Az[0], Bh0, Dz); Dz = mfma16(Az[1], Bh1, Dz);
      Dn = mfma16(Anh[0], Bh0, Dn); Dn = mfma16(Anh[1], Bh1, Dn);
    }

    // phase 1a (all waves): partial dot over this wave's 8 h-pairs
    {
      const uint4* hr = &sH4[t][0];
      uint4 ha = hr[2*w];
      uint4 hb = hr[2*w+1];
      float cA = 0.f;
      float cB = (w == 3) ? ((u < SP) ? sZdc[t][u] : 0.f) : 0.f;
      cA = fdot2_(wc[0], ha.x, cA); cB = fdot2_(wc[1], ha.y, cB);
      cA = fdot2_(wc[2], ha.z, cA); cB = fdot2_(wc[3], ha.w, cB);
      cA = fdot2_(wc[4], hb.x, cA); cB = fdot2_(wc[5], hb.y, cB);
      if (w < 3){ cA = fdot2_(wc[6], hb.z, cA); cB = fdot2_(wc[7], hb.w, cB); }
      sPart[w][u] = cA + cB;
    }
    __syncthreads();   // P: partials + all pre-P h reads done

    // post-P: every wave combines redundantly (no wave0 serialization)
    float acc = (sPart[0][u] + sPart[1][u]) + (sPart[2][u] + sPart[3][u]);
    float rv = bwd ? acc : tanh_(acc);
    if (w == 0){
      if (u < SP) rho[((size_t)t*BATCH + b)*SP + u] = rv;  // fire & forget
      const int slot = bwd ? t : (t - (NN-OO));
      if (slot >= 0 && slot < 8 && u < SP)
        *(f16*)((char*)&sRhoHist[slot][0] + 2*u) = (f16)rv;
    }

    if (act){
      // build Br0/Br1 in-register: lane needs rho[8q..8q+8) and [32+8q..)
      const float rvm = (u < SP) ? rv : ((u == 63) ? 1.f : 0.f);
      const int rvb = __builtin_bit_cast(int, rvm);
      uint4 B0, B1;
      {
        u32 w0[4], w1[4];
        #pragma unroll
        for (int j=0;j<4;j++){
          const int i0 = (8*q + 2*j)*4;
          int a0 = __builtin_amdgcn_ds_bpermute(i0,     rvb);
          int a1 = __builtin_amdgcn_ds_bpermute(i0+4,   rvb);
          int c0 = __builtin_amdgcn_ds_bpermute(i0+128, rvb);
          int c1 = __builtin_amdgcn_ds_bpermute(i0+132, rvb);
          w0[j] = pack2(__builtin_bit_cast(float,a0), __builtin_bit_cast(float,a1));
          w1[j] = pack2(__builtin_bit_cast(float,c0), __builtin_bit_cast(float,c1));
        }
        B0.x=w0[0]; B0.y=w0[1]; B0.z=w0[2]; B0.w=w0[3];
        B1.x=w1[0]; B1.y=w1[1]; B1.z=w1[2]; B1.w=w1[3];
      }
      const f16x8 Br0 = bc16(B0);
      const f16x8 Br1 = bc16(B1);

      f32x4 Gn={0,0,0,0};
      Gn = mfma16(Ani[0], Br0, Gn);
      Gn = mfma16(Ani[1], Br1, Gn);

      // finish group 0 (rho-dependent MFMA halves) + gates
      Dr = mfma16(Ar[2], Br0, Dr); Dr = mfma16(Ar[3], Br1, Dr);
      Dz = mfma16(Az[2], Br0, Dz); Dz = mfma16(Az[3], Br1, Dz);
      gates(Dr, Dz, Dn, Gn, ci0, ml < cnt, 1.0f);

      // group 1 (rare): rows disjoint from group 0 -> barrier-free
      if (cnt > 16){
        const int idxp = 16 + ml;
        const int ci = (idxp < cnt) ? (int)sConsL[t][idxp] : 64;
        const f16x8 Bh0 = bc16(sH4[ci][q]);
        const f16x8 Bh1 = bc16(sH4[ci][4+q]);
        fullpass(Bh0, Bh1, Br0, Br1, Gn, ci, idxp < cnt, 1.0f);
      }
    }
    __syncthreads();   // C: h writes visible to next step's reads
  }

  // ---- alpha tail: 8 GRU steps on scratch row 64 ----
  for (int s2=0; s2<8; s2++){
    const int i = bwd ? (7 - s2) : (NN - OO + s2);
    const int slot = bwd ? i : (i - (NN-OO));
    const f16x8 Th0 = bc16(sH4[64][q]);
    const f16x8 Th1 = bc16(sH4[64][4+q]);
    const f16x8 Tr0 = bc16(sRhoHist[slot][q]);
    const f16x8 Tr1 = bc16(sRhoHist[slot][4+q]);
    f32x4 Gt={0,0,0,0};
    Gt = mfma16(Ani[0], Tr0, Gt);
    Gt = mfma16(Ani[1], Tr1, Gt);
    __syncthreads();   // all waves' row-64 reads done before writes
    fullpass(Th0, Th1, Tr0, Tr1, Gt, 64, ml==0, sHas[i]);
    __syncthreads();   // writes visible to next tail step
  }
  if (tid < SP) alpha[(size_t)b*SP + tid] = (float)*(const f16*)(ROWB(64) + 2*tid);
  #undef ROWB
}

// One block per batch element: psi + softmaxes, omega, value -> d_out directly.
__global__ __launch_bounds__(256, 1) void head_kernel(float* __restrict__ ws,
                                                      void* __restrict__ outp)
{
  const int b = blockIdx.x;
  const int tid = threadIdx.x;
  const int isbf = (ws[OFF_FLAG] != 0.f);
  const float* hasc   = ws + OFF_HAS;
  const float* WaC    = ws + OFF_WA;
  const float* baC    = ws + OFF_BA;
  const float* WcC    = ws + OFF_WC;
  const float* bcC    = ws + OFF_BC;
  const float* WuC    = ws + OFF_WU;
  const float* buC    = ws + OFF_BU;
  const float* rhoF   = ws + OFF_RHOF;
  const float* rhoB   = ws + OFF_RHOB;
  const float* alphaF = ws + OFF_ALF;
  const float* alphaB = ws + OFF_ALB;

  __shared__ float sF[NN][121];
  __shared__ float sAB[120];
  __shared__ float sWu[NR*120];
  __shared__ float sHasR[NN];
  __shared__ float sPsi[NR][NN];
  __shared__ float sRed[NR][2];
  __shared__ float sOm[NA];

  auto wout = [&](int idx, float v){
    if (isbf) ((u16*)outp)[idx] = f2bf(v);
    else      ((float*)outp)[idx] = v;
  };

  for (int idx=tid; idx<NN*SP; idx+=256){
    int n = idx/SP, s = idx%SP;
    sF[n][s]    = rhoF[((size_t)n*BATCH + b)*SP + s];
    sF[n][60+s] = rhoB[((size_t)n*BATCH + b)*SP + s];
  }
  for (int idx=tid; idx<120; idx+=256)
    sAB[idx] = (idx<60) ? alphaF[(size_t)b*SP + idx] : alphaB[(size_t)b*SP + idx-60];
  for (int idx=tid; idx<NR*120; idx+=256) sWu[idx] = WuC[idx];
  for (int idx=tid; idx<NN; idx+=256) sHasR[idx] = hasc[b*NN + idx];
  __syncthreads();

  for (int idx=tid; idx<NR*NN; idx+=256){
    int r = idx/NN, n = idx%NN;
    float acc = buC[r];
    for (int s=0;s<120;s++) acc += sF[n][s]*sWu[r*120+s];
    sPsi[r][n] = (sHasR[n] != 0.f) ? acc : -60.f;
  }
  if (tid >= 64 && tid < 64+NA){
    int a = tid - 64;
    float acc = baC[a];
    for (int s=0;s<120;s++) acc += sAB[s]*WaC[a*120+s];
    sOm[a] = acc;
  }
  if (tid == 70){
    float acc = bcC[0];
    for (int s=0;s<120;s++) acc += sAB[s]*WcC[s];
    wout(2560 + BATCH*NR*NN + b, acc);                 // value
  }
  __syncthreads();

  if (tid < NR){
    float m = -1e30f;
    for (int n=0;n<NN;n++) m = fmaxf(m, sPsi[tid][n]);
    float ssum = 0.f;
    for (int n=0;n<NN;n++) ssum += __expf(sPsi[tid][n]-m);
    sRed[tid][0] = m; sRed[tid][1] = 1.f/ssum;
  }
  if (tid == 8){
    float m = -1e30f;
    for (int a=0;a<NA;a++) m = fmaxf(m, sOm[a]);
    float e[NA]; float ssum = 0.f;
    for (int a=0;a<NA;a++){ e[a] = __expf(sOm[a]-m); ssum += e[a]; }
    for (int a=0;a<NA;a++) wout(b*NA + a, e[a]/ssum);  // instr_prob
  }
  __syncthreads();

  for (int idx=tid; idx<NR*NN; idx+=256){
    int r = idx/NN, n = idx%NN;
    float v = __expf(sPsi[r][n]-sRed[r][0]) * sRed[r][1];
    wout(2560 + (size_t)b*NR*NN + idx, v);             // role_prob
  }
}

extern "C" void kernel_launch(void* const* d_in, const int* in_sizes, int n_in,
                              void* d_out, int out_size, void* d_ws, size_t ws_size,
                              hipStream_t stream)
{
  const int* adj = (const int*)d_in[3];
  float* ws = (float*)d_ws;

  conv_in<<<(CONV_TOTAL+255)/256, 256, 0, stream>>>(
      d_in[0], d_in[1], d_in[2],
      d_in[4], d_in[5], d_in[6], d_in[7],
      d_in[8], d_in[9], d_in[10], d_in[11],
      d_in[12], d_in[13], d_in[14], d_in[15],
      d_in[16], d_in[17], d_in[18], d_in[19],
      d_in[20], d_in[21], ws);

  dir_kernel<<<1024, 256, 0, stream>>>(adj, ws);

  head_kernel<<<512, 256, 0, stream>>>(ws, d_out);
}

// Round 5
// 281.700 us; speedup vs baseline: 1.0345x; 1.0345x over previous
//
#include <hip/hip_runtime.h>
#include <hip/hip_bf16.h>

#define NN 64
#define BATCH 512
#define SP 60
#define SG 180
#define SEX 10
#define CATD 80
#define NA 5
#define NR 7
#define OO 8
#define II 8

typedef unsigned long long u64;
typedef unsigned short u16;
typedef unsigned int u32;
typedef unsigned char u8;

// ---- workspace layout (float offsets) ----
#define OFF_Z     0
#define OFF_DZ    327680
#define OFF_HAS   655360
#define OFF_WIHF  688128
#define OFF_WHHF  698928
#define OFF_BIHF  709728
#define OFF_BHHF  709908
#define OFF_WIHB  710088
#define OFF_WHHB  720888
#define OFF_BIHB  731688
#define OFF_BHHB  731868
#define OFF_WF    732048
#define OFF_BF    736848
#define OFF_WB    736908
#define OFF_BB    741708
#define OFF_WA    741768
#define OFF_BA    742368
#define OFF_WC    742373
#define OFF_BC    742493
#define OFF_WU    742494
#define OFF_BU    743334
#define CONV_TOTAL 743341
#define OFF_FLAG  743342
#define OFF_RHOF  743344
#define OFF_RHOB  (OFF_RHOF + 1966080)
#define OFF_ALF   (OFF_RHOB + 1966080)
#define OFF_ALB   (OFF_ALF + 30720)
#define OUT_TOTAL 232448

typedef _Float16 f16;
typedef _Float16 half2_t __attribute__((ext_vector_type(2)));
typedef _Float16 f16x8 __attribute__((ext_vector_type(8)));
typedef float f32x4 __attribute__((ext_vector_type(4)));

__device__ __forceinline__ float us2f(u16 v){
  return __uint_as_float(((u32)v) << 16);
}
__device__ __forceinline__ u16 f2bf(float f){
  __hip_bfloat16 h = __float2bfloat16(f);
  return *reinterpret_cast<u16*>(&h);
}
__device__ __forceinline__ float rcp_(float x){ return __builtin_amdgcn_rcpf(x); }
__device__ __forceinline__ float sigm(float x){
  return rcp_(1.f + __expf(-x));
}
__device__ __forceinline__ float tanh_(float x){
  float e = __expf(2.f*fabsf(x));
  float t = 1.f - 2.f*rcp_(e + 1.f);
  return copysignf(t, x);
}
__device__ __forceinline__ u32 pack2(float a, float b){
  half2_t h; h[0] = (f16)a; h[1] = (f16)b;
  return __builtin_bit_cast(u32, h);
}
__device__ __forceinline__ float fdot2_(u32 a, u32 b, float c){
  return __builtin_amdgcn_fdot2(__builtin_bit_cast(half2_t, a),
                                __builtin_bit_cast(half2_t, b), c, false);
}
__device__ __forceinline__ f16x8 bc16(uint4 v){ return __builtin_bit_cast(f16x8, v); }
__device__ __forceinline__ f32x4 mfma16(f16x8 a, f16x8 b, f32x4 c){
  return __builtin_amdgcn_mfma_f32_16x16x32_f16(a, b, c, 0, 0, 0);
}

// has is exactly {0,1}. f32 words: only 0x00000000 / 0x3F800000.
// bf16-pair words: 0x3F803F80 == (1.0,1.0) appears w.p. ~0.81 per pair.
__device__ __forceinline__ int detect_bf16(const u32* w){
  int f = 0;
  for (int i=0;i<256;i++) f |= (w[i] == 0x3F803F80u) ? 1 : 0;
  return f;
}

__global__ __launch_bounds__(256) void conv_in(
  const void* z, const void* dz, const void* has,
  const void* WihF, const void* WhhF, const void* bihF, const void* bhhF,
  const void* WihB, const void* WhhB, const void* bihB, const void* bhhB,
  const void* Wf_, const void* bf_, const void* Wb_, const void* bb_,
  const void* Wa, const void* ba, const void* Wc, const void* bc,
  const void* Wu, const void* bu, float* ws)
{
  const int isbf = detect_bf16((const u32*)has);
  if (blockIdx.x == 0 && threadIdx.x == 0) ws[OFF_FLAG] = (float)isbf;
  int idx = blockIdx.x*256 + threadIdx.x;
  if (idx >= CONV_TOTAL) return;
  const void* src; int loc;
  if      (idx < OFF_DZ  ){ src=z;    loc=idx-OFF_Z;    }
  else if (idx < OFF_HAS ){ src=dz;   loc=idx-OFF_DZ;   }
  else if (idx < OFF_WIHF){ src=has;  loc=idx-OFF_HAS;  }
  else if (idx < OFF_WHHF){ src=WihF; loc=idx-OFF_WIHF; }
  else if (idx < OFF_BIHF){ src=WhhF; loc=idx-OFF_WHHF; }
  else if (idx < OFF_BHHF){ src=bihF; loc=idx-OFF_BIHF; }
  else if (idx < OFF_WIHB){ src=bhhF; loc=idx-OFF_BHHF; }
  else if (idx < OFF_WHHB){ src=WihB; loc=idx-OFF_WIHB; }
  else if (idx < OFF_BIHB){ src=WhhB; loc=idx-OFF_WHHB; }
  else if (idx < OFF_BHHB){ src=bihB; loc=idx-OFF_BIHB; }
  else if (idx < OFF_WF  ){ src=bhhB; loc=idx-OFF_BHHB; }
  else if (idx < OFF_BF  ){ src=Wf_;  loc=idx-OFF_WF;   }
  else if (idx < OFF_WB  ){ src=bf_;  loc=idx-OFF_BF;   }
  else if (idx < OFF_BB  ){ src=Wb_;  loc=idx-OFF_WB;   }
  else if (idx < OFF_WA  ){ src=bb_;  loc=idx-OFF_BB;   }
  else if (idx < OFF_BA  ){ src=Wa;   loc=idx-OFF_WA;   }
  else if (idx < OFF_WC  ){ src=ba;   loc=idx-OFF_BA;   }
  else if (idx < OFF_BC  ){ src=Wc;   loc=idx-OFF_WC;   }
  else if (idx < OFF_WU  ){ src=bc;   loc=idx-OFF_BC;   }
  else if (idx < OFF_BU  ){ src=Wu;   loc=idx-OFF_WU;   }
  else                    { src=bu;   loc=idx-OFF_BU;   }
  float v = isbf ? us2f(((const u16*)src)[loc]) : ((const float*)src)[loc];
  ws[idx] = v;
}

// r16: r14 structure (best: 157us) + safe r15 pieces only.
//  - barrier B removed: group-0/1 Bh fragments + their 6 h-dependent MFMAs
//    hoisted pre-P (P separates all full-row h reads from post-A writes);
//    groups p>=2 read rows disjoint from earlier groups' writes -> no bar
//  - KEEP wave0 combine + f16 sRhoPad broadcast + barrier A + ds_read_b128
//    (r15's bpermute/redundant-combine replacement regressed 157->183)
// Step: [Bh preload+6MFMA+phase1a] -> P -> [w0 combine] -> A ->
//       [Br read+Gn+5MFMA+gates(+extra groups)] -> C.  3 barriers/step.
__global__ __launch_bounds__(256, 4) void dir_kernel(const int* __restrict__ adj,
                                                     float* __restrict__ ws)
{
  const int tid = threadIdx.x;
  const int w   = tid >> 6;         // wave id (0..3) == row tile mt
  const int u   = tid & 63;         // lane
  const int ml  = u & 15;           // MFMA col (consumer slot)
  const int q   = u >> 4;           // MFMA quad
  const int bid = blockIdx.x;
  const int bwd = bid >> 9;
  const int b   = bid & 511;

  const float* Wih  = ws + (bwd ? OFF_WIHB : OFF_WIHF);
  const float* Whh  = ws + (bwd ? OFF_WHHB : OFF_WHHF);
  const float* bih  = ws + (bwd ? OFF_BIHB : OFF_BIHF);
  const float* bhh  = ws + (bwd ? OFF_BHHB : OFF_BHHF);
  const float* Wcat = ws + (bwd ? OFF_WB   : OFF_WF);
  const float* bcat = ws + (bwd ? OFF_BB   : OFF_BF);
  const float* zc   = ws + OFF_Z;
  const float* dzc  = ws + OFF_DZ;
  const float* hasc = ws + OFF_HAS;
  float* rho   = ws + (bwd ? OFF_RHOB : OFF_RHOF);  // [64][512][60]
  float* alpha = ws + (bwd ? OFF_ALB  : OFF_ALF);   // [512][60]

  __shared__ uint4 sH4[65][9];        // h rows, 144B stride; half63=1.0 (bias ch)
  __shared__ uint4 sRhoPad[8];        // rho_t halves; half63=1.0
  __shared__ uint4 sRhoHist[8][8];    // tail rho history; half63=1.0
  __shared__ float sZdc[NN][SP];      // precomputed bias + z/dz contribution
  __shared__ float sPart[4][64];      // phase-1 partials per wave
  __shared__ u32 sZp[NN][5];
  __shared__ u32 sDZp[NN][5];
  __shared__ float sHas[NN];
  __shared__ u64 sRowM[NN];
  __shared__ u8 sConsL[NN][64];       // consumer lists (batch-independent)
  __shared__ int sConsCnt[NN];

  #define ROWB(I) ((char*)&sH4[(I)][0])
  const u32 BIASW = 0x3C000000u;      // halves {0, 1.0h}

  // ---- staging ----
  {
    if (tid < 64){
      u64 rowm = 0;
      for (int j=0;j<64;j++) rowm |= ((u64)(adj[tid*64+j]!=0))<<j;
      sRowM[tid] = rowm;
      sHas[tid] = hasc[b*NN + tid];
    }
    for (int idx=tid; idx<65*9; idx+=256){
      uint4 v = {0,0,0,0};
      if (idx % 9 == 7) v.w = BIASW;         // half63 = 1.0
      ((uint4*)sH4)[idx] = v;
    }
    if (tid < 8){ uint4 v={0,0,0,0}; if (tid==7) v.w = BIASW; sRhoPad[tid]=v; }
    if (tid < 64){ uint4 v={0,0,0,0}; if ((tid&7)==7) v.w = BIASW; ((uint4*)sRhoHist)[tid]=v; }
    for (int idx=tid; idx<NN*5; idx+=256){
      int n2=idx/5, p2=idx%5;
      sZp [n2][p2] = pack2(zc [(size_t)b*NN*SEX + n2*SEX + 2*p2],
                           zc [(size_t)b*NN*SEX + n2*SEX + 2*p2+1]);
      sDZp[n2][p2] = pack2(dzc[(size_t)b*NN*SEX + n2*SEX + 2*p2],
                           dzc[(size_t)b*NN*SEX + n2*SEX + 2*p2+1]);
    }
  }
  __syncthreads();
  if (tid < 64){
    u64 cm = 0;
    if (bwd) for (int i2=0;i2<64;i2++) cm |= ((sRowM[i2]>>tid)&1ULL)<<i2;
    u64 m = bwd ? cm : sRowM[tid];          // consumers of node tid
    int c = 0;
    while (m){ int i2 = (int)__builtin_ctzll(m); m &= m-1; sConsL[tid][c++] = (u8)i2; }
    sConsCnt[tid] = c;
  }
  // zdc precompute: sZdc[t][uu] = bcat[uu] + Wz.z_t + Wdz.dz_t (bias folded).
  // Wave tw handles t = tw, tw+4, ...; weights transient (staging only).
  {
    const int uu = tid & 63;
    const int tw = tid >> 6;
    if (uu < SP){
      u32 wz[10];
      #pragma unroll
      for (int p=0;p<10;p++)
        wz[p] = pack2(Wcat[uu*CATD + 60 + 2*p], Wcat[uu*CATD + 60 + 2*p + 1]);
      const float bb0 = bcat[uu];
      for (int t2=tw; t2<NN; t2+=4){
        float c = bb0;
        #pragma unroll
        for (int p=0;p<5;p++){
          c = fdot2_(wz[p],   sZp [t2][p], c);
          c = fdot2_(wz[5+p], sDZp[t2][p], c);
        }
        sZdc[t2][uu] = c;
      }
    }
  }

  // ---- A fragments (wave w owns mt = w): lane (q,ml) holds
  // A[row=16w+ml][K=32kt+8q+j] ----
  // Ar/Az: K<60 Whh, 64<=K<124 Wih, K==127 bias (bhh+bih).
  // Anh:   K<60 Whh_n, K==63 bias bhh_n.   Ani: K<60 Wih_n, K==63 bias bih_n.
  f16x8 Ar[4], Az[4], Anh[2], Ani[2];
  {
    const int R = 16*w + ml;
    const bool rok = (R < SP);
    #pragma unroll
    for (int kt=0; kt<4; kt++){
      f16x8 vr, vz;
      #pragma unroll
      for (int j=0;j<8;j++){
        const int K = 32*kt + 8*q + j;
        float wr=0.f, wz2=0.f;
        if (rok){
          if (K < SP){ wr = Whh[R*SP+K]; wz2 = Whh[(60+R)*SP+K]; }
          else if (K >= 64 && K < 64+SP){ wr = Wih[R*SP+(K-64)]; wz2 = Wih[(60+R)*SP+(K-64)]; }
          else if (K == 127){ wr = bhh[R]+bih[R]; wz2 = bhh[60+R]+bih[60+R]; }
        }
        vr[j]=(f16)wr; vz[j]=(f16)wz2;
      }
      Ar[kt]=vr; Az[kt]=vz;
    }
    #pragma unroll
    for (int kt=0; kt<2; kt++){
      f16x8 vn, vi;
      #pragma unroll
      for (int j=0;j<8;j++){
        const int K = 32*kt + 8*q + j;
        float wn=0.f, wi=0.f;
        if (rok){
          if (K < SP){ wn = Whh[(120+R)*SP+K]; wi = Wih[(120+R)*SP+K]; }
          else if (K == 63){ wn = bhh[120+R]; wi = bih[120+R]; }
        }
        vn[j]=(f16)wn; vi[j]=(f16)wi;
      }
      Anh[kt]=vn; Ani[kt]=vi;
    }
  }

  // phase-1 h-weights, distributed: wave w owns pairs 8w..8w+7 (wave 3: 6)
  u32 wc[8];
  #pragma unroll
  for (int k=0;k<8;k++){
    const int kk = 8*w + k;
    wc[k] = (kk < 30) ? pack2(Wcat[u*CATD + 2*kk], Wcat[u*CATD + 2*kk + 1]) : 0u;
  }
  __syncthreads();   // lists + zdc + LDS init visible

  // gates: in-register GRU gate math + h read-modify-write for row tile w,
  // consumer ci, slot column ml. Each wave touches only bytes [32w,32w+32)
  // of the row -> no cross-wave overlap; hold-read is in the wave's own
  // window, so it needs no barrier vs other waves' full-row reads (pre-P).
  auto gates = [&](f32x4 Dr, f32x4 Dz, f32x4 Dn, f32x4 Gn,
                   int ci, bool wr, float bl){
    char* rp = ROWB(ci) + 32*w + 8*q;
    uint2 h2 = *(uint2*)rp;
    half2_t ha = __builtin_bit_cast(half2_t, h2.x);
    half2_t hb = __builtin_bit_cast(half2_t, h2.y);
    float hold[4] = { (float)ha[0], (float)ha[1], (float)hb[0], (float)hb[1] };
    float hw[4];
    #pragma unroll
    for (int reg=0;reg<4;reg++){
      float r_ = sigm(Dr[reg]);
      float zg = sigm(Dz[reg]);
      float nv = tanh_(Gn[reg] + r_*Dn[reg]);
      float hn_ = (1.f - zg)*nv + zg*hold[reg];
      hw[reg] = (bl != 0.f) ? hn_ : hold[reg];   // bl is exactly 0 or 1
    }
    if (wr && !(w==3 && q==3)){
      uint2 o; o.x = pack2(hw[0],hw[1]); o.y = pack2(hw[2],hw[3]);
      *(uint2*)rp = o;
    }
  };

  // full 11-MFMA pass (groups p>=2 + tail)
  auto fullpass = [&](f16x8 Bh0, f16x8 Bh1, f16x8 Br0, f16x8 Br1,
                      f32x4 Gn, int ci, bool wr, float bl){
    f32x4 Dr={0,0,0,0}, Dz={0,0,0,0}, Dn={0,0,0,0};
    Dr = mfma16(Ar[0], Bh0, Dr); Dr = mfma16(Ar[1], Bh1, Dr);
    Dr = mfma16(Ar[2], Br0, Dr); Dr = mfma16(Ar[3], Br1, Dr);
    Dz = mfma16(Az[0], Bh0, Dz); Dz = mfma16(Az[1], Bh1, Dz);
    Dz = mfma16(Az[2], Br0, Dz); Dz = mfma16(Az[3], Br1, Dz);
    Dn = mfma16(Anh[0], Bh0, Dn); Dn = mfma16(Anh[1], Bh1, Dn);
    gates(Dr, Dz, Dn, Gn, ci, wr, bl);
  };

  // ---- 64 pipelined steps, 3 barriers each ----
  int t = bwd ? 63 : 0;
  const int dt = bwd ? -1 : 1;
  for (int s=0; s<64; s++, t+=dt){
    const float blendT = sHas[t];
    const int cnt = sConsCnt[t];
    const bool act = (blendT != 0.f) && (cnt > 0);   // block-uniform
    const bool g1  = act && (cnt > 16);

    // pre-P: group-0/1 Bh preload + h-dependent MFMA halves (overlaps
    // the phase-1a fdot2 chain; reads precede all of this step's writes)
    f32x4 Dr={0,0,0,0}, Dz={0,0,0,0}, Dn={0,0,0,0};
    f32x4 Dr2={0,0,0,0}, Dz2={0,0,0,0}, Dn2={0,0,0,0};
    int ci0 = 64, ci1 = 64;
    if (act){
      ci0 = (ml < cnt) ? (int)sConsL[t][ml] : 64;
      const f16x8 Bh0 = bc16(sH4[ci0][q]);
      const f16x8 Bh1 = bc16(sH4[ci0][4+q]);
      Dr = mfma16(Ar[0], Bh0, Dr); Dr = mfma16(Ar[1], Bh1, Dr);
      Dz = mfma16(Az[0], Bh0, Dz); Dz = mfma16(Az[1], Bh1, Dz);
      Dn = mfma16(Anh[0], Bh0, Dn); Dn = mfma16(Anh[1], Bh1, Dn);
      if (g1){
        ci1 = (16 + ml < cnt) ? (int)sConsL[t][16 + ml] : 64;
        const f16x8 Ch0 = bc16(sH4[ci1][q]);
        const f16x8 Ch1 = bc16(sH4[ci1][4+q]);
        Dr2 = mfma16(Ar[0], Ch0, Dr2); Dr2 = mfma16(Ar[1], Ch1, Dr2);
        Dz2 = mfma16(Az[0], Ch0, Dz2); Dz2 = mfma16(Az[1], Ch1, Dz2);
        Dn2 = mfma16(Anh[0], Ch0, Dn2); Dn2 = mfma16(Anh[1], Ch1, Dn2);
      }
    }

    // phase 1a (all waves): partial dot over this wave's 8 h-pairs
    {
      const uint4* hr = &sH4[t][0];
      uint4 ha = hr[2*w];
      uint4 hb = hr[2*w+1];
      float cA = 0.f;
      float cB = (w == 3) ? ((u < SP) ? sZdc[t][u] : 0.f) : 0.f;
      cA = fdot2_(wc[0], ha.x, cA); cB = fdot2_(wc[1], ha.y, cB);
      cA = fdot2_(wc[2], ha.z, cA); cB = fdot2_(wc[3], ha.w, cB);
      cA = fdot2_(wc[4], hb.x, cA); cB = fdot2_(wc[5], hb.y, cB);
      if (w < 3){ cA = fdot2_(wc[6], hb.z, cA); cB = fdot2_(wc[7], hb.w, cB); }
      sPart[w][u] = cA + cB;
    }
    __syncthreads();   // P: partials + all pre-P h reads done

    // wave0: combine + activation + rho broadcast/stores
    if (w == 0){
      float acc = (sPart[0][u] + sPart[1][u]) + (sPart[2][u] + sPart[3][u]);
      float rv = bwd ? acc : tanh_(acc);
      if (u < SP){
        rho[((size_t)t*BATCH + b)*SP + u] = rv;   // fire & forget
        *(f16*)((char*)&sRhoPad[0] + 2*u) = (f16)rv;
      }
      const int slot = bwd ? t : (t - (NN-OO));
      if (slot >= 0 && slot < 8 && u < SP)
        *(f16*)((char*)&sRhoHist[slot][0] + 2*u) = (f16)rv;
    }
    __syncthreads();   // A: rho visible to all waves

    if (act){
      const f16x8 Br0 = bc16(sRhoPad[q]);
      const f16x8 Br1 = bc16(sRhoPad[4+q]);
      f32x4 Gn={0,0,0,0};
      Gn = mfma16(Ani[0], Br0, Gn);
      Gn = mfma16(Ani[1], Br1, Gn);

      // finish group 0 (rho-dependent halves) + gates
      Dr = mfma16(Ar[2], Br0, Dr); Dr = mfma16(Ar[3], Br1, Dr);
      Dz = mfma16(Az[2], Br0, Dz); Dz = mfma16(Az[3], Br1, Dz);
      gates(Dr, Dz, Dn, Gn, ci0, ml < cnt, 1.0f);

      if (g1){
        Dr2 = mfma16(Ar[2], Br0, Dr2); Dr2 = mfma16(Ar[3], Br1, Dr2);
        Dz2 = mfma16(Az[2], Br0, Dz2); Dz2 = mfma16(Az[3], Br1, Dz2);
        gates(Dr2, Dz2, Dn2, Gn, ci1, 16 + ml < cnt, 1.0f);
      }

      // groups p>=2 (absent for this input, kept for generality): rows
      // disjoint from groups 0/1 writes -> barrier-free
      for (int p=2; 16*p < cnt; p++){
        const int idxp = 16*p + ml;
        const int ci = (idxp < cnt) ? (int)sConsL[t][idxp] : 64;
        const f16x8 Bh0 = bc16(sH4[ci][q]);
        const f16x8 Bh1 = bc16(sH4[ci][4+q]);
        fullpass(Bh0, Bh1, Br0, Br1, Gn, ci, idxp < cnt, 1.0f);
      }
    }
    __syncthreads();   // C: h writes visible to next step's reads
  }

  // ---- alpha tail: 8 GRU steps on scratch row 64 ----
  for (int s2=0; s2<8; s2++){
    const int i = bwd ? (7 - s2) : (NN - OO + s2);
    const int slot = bwd ? i : (i - (NN-OO));
    const f16x8 Th0 = bc16(sH4[64][q]);
    const f16x8 Th1 = bc16(sH4[64][4+q]);
    const f16x8 Tr0 = bc16(sRhoHist[slot][q]);
    const f16x8 Tr1 = bc16(sRhoHist[slot][4+q]);
    f32x4 Gt={0,0,0,0};
    Gt = mfma16(Ani[0], Tr0, Gt);
    Gt = mfma16(Ani[1], Tr1, Gt);
    __syncthreads();   // all waves' row-64 reads done before writes
    fullpass(Th0, Th1, Tr0, Tr1, Gt, 64, ml==0, sHas[i]);
    __syncthreads();   // writes visible to next tail step
  }
  if (tid < SP) alpha[(size_t)b*SP + tid] = (float)*(const f16*)(ROWB(64) + 2*tid);
  #undef ROWB
}

// One block per batch element: psi + softmaxes, omega, value -> d_out directly.
__global__ __launch_bounds__(256, 1) void head_kernel(float* __restrict__ ws,
                                                      void* __restrict__ outp)
{
  const int b = blockIdx.x;
  const int tid = threadIdx.x;
  const int isbf = (ws[OFF_FLAG] != 0.f);
  const float* hasc   = ws + OFF_HAS;
  const float* WaC    = ws + OFF_WA;
  const float* baC    = ws + OFF_BA;
  const float* WcC    = ws + OFF_WC;
  const float* bcC    = ws + OFF_BC;
  const float* WuC    = ws + OFF_WU;
  const float* buC    = ws + OFF_BU;
  const float* rhoF   = ws + OFF_RHOF;
  const float* rhoB   = ws + OFF_RHOB;
  const float* alphaF = ws + OFF_ALF;
  const float* alphaB = ws + OFF_ALB;

  __shared__ float sF[NN][121];
  __shared__ float sAB[120];
  __shared__ float sWu[NR*120];
  __shared__ float sHasR[NN];
  __shared__ float sPsi[NR][NN];
  __shared__ float sRed[NR][2];
  __shared__ float sOm[NA];

  auto wout = [&](int idx, float v){
    if (isbf) ((u16*)outp)[idx] = f2bf(v);
    else      ((float*)outp)[idx] = v;
  };

  for (int idx=tid; idx<NN*SP; idx+=256){
    int n = idx/SP, s = idx%SP;
    sF[n][s]    = rhoF[((size_t)n*BATCH + b)*SP + s];
    sF[n][60+s] = rhoB[((size_t)n*BATCH + b)*SP + s];
  }
  for (int idx=tid; idx<120; idx+=256)
    sAB[idx] = (idx<60) ? alphaF[(size_t)b*SP + idx] : alphaB[(size_t)b*SP + idx-60];
  for (int idx=tid; idx<NR*120; idx+=256) sWu[idx] = WuC[idx];
  for (int idx=tid; idx<NN; idx+=256) sHasR[idx] = hasc[b*NN + idx];
  __syncthreads();

  for (int idx=tid; idx<NR*NN; idx+=256){
    int r = idx/NN, n = idx%NN;
    float acc = buC[r];
    for (int s=0;s<120;s++) acc += sF[n][s]*sWu[r*120+s];
    sPsi[r][n] = (sHasR[n] != 0.f) ? acc : -60.f;
  }
  if (tid >= 64 && tid < 64+NA){
    int a = tid - 64;
    float acc = baC[a];
    for (int s=0;s<120;s++) acc += sAB[s]*WaC[a*120+s];
    sOm[a] = acc;
  }
  if (tid == 70){
    float acc = bcC[0];
    for (int s=0;s<120;s++) acc += sAB[s]*WcC[s];
    wout(2560 + BATCH*NR*NN + b, acc);                 // value
  }
  __syncthreads();

  if (tid < NR){
    float m = -1e30f;
    for (int n=0;n<NN;n++) m = fmaxf(m, sPsi[tid][n]);
    float ssum = 0.f;
    for (int n=0;n<NN;n++) ssum += __expf(sPsi[tid][n]-m);
    sRed[tid][0] = m; sRed[tid][1] = 1.f/ssum;
  }
  if (tid == 8){
    float m = -1e30f;
    for (int a=0;a<NA;a++) m = fmaxf(m, sOm[a]);
    float e[NA]; float ssum = 0.f;
    for (int a=0;a<NA;a++){ e[a] = __expf(sOm[a]-m); ssum += e[a]; }
    for (int a=0;a<NA;a++) wout(b*NA + a, e[a]/ssum);  // instr_prob
  }
  __syncthreads();

  for (int idx=tid; idx<NR*NN; idx+=256){
    int r = idx/NN, n = idx%NN;
    float v = __expf(sPsi[r][n]-sRed[r][0]) * sRed[r][1];
    wout(2560 + (size_t)b*NR*NN + idx, v);             // role_prob
  }
}

extern "C" void kernel_launch(void* const* d_in, const int* in_sizes, int n_in,
                              void* d_out, int out_size, void* d_ws, size_t ws_size,
                              hipStream_t stream)
{
  const int* adj = (const int*)d_in[3];
  float* ws = (float*)d_ws;

  conv_in<<<(CONV_TOTAL+255)/256, 256, 0, stream>>>(
      d_in[0], d_in[1], d_in[2],
      d_in[4], d_in[5], d_in[6], d_in[7],
      d_in[8], d_in[9], d_in[10], d_in[11],
      d_in[12], d_in[13], d_in[14], d_in[15],
      d_in[16], d_in[17], d_in[18], d_in[19],
      d_in[20], d_in[21], ws);

  dir_kernel<<<1024, 256, 0, stream>>>(adj, ws);

  head_kernel<<<512, 256, 0, stream>>>(ws, d_out);
}

// Round 6
// 272.893 us; speedup vs baseline: 1.0679x; 1.0323x over previous
//
#include <hip/hip_runtime.h>
#include <hip/hip_bf16.h>

#define NN 64
#define BATCH 512
#define SP 60
#define SG 180
#define SEX 10
#define CATD 80
#define NA 5
#define NR 7
#define OO 8
#define II 8

typedef unsigned long long u64;
typedef unsigned short u16;
typedef unsigned int u32;
typedef unsigned char u8;

// ---- workspace layout (float offsets) ----
#define OFF_Z     0
#define OFF_DZ    327680
#define OFF_HAS   655360
#define OFF_WIHF  688128
#define OFF_WHHF  698928
#define OFF_BIHF  709728
#define OFF_BHHF  709908
#define OFF_WIHB  710088
#define OFF_WHHB  720888
#define OFF_BIHB  731688
#define OFF_BHHB  731868
#define OFF_WF    732048
#define OFF_BF    736848
#define OFF_WB    736908
#define OFF_BB    741708
#define OFF_WA    741768
#define OFF_BA    742368
#define OFF_WC    742373
#define OFF_BC    742493
#define OFF_WU    742494
#define OFF_BU    743334
#define CONV_TOTAL 743341
#define OFF_FLAG  743342
#define OFF_RHOF  743344
#define OFF_RHOB  (OFF_RHOF + 1966080)
#define OFF_ALF   (OFF_RHOB + 1966080)
#define OFF_ALB   (OFF_ALF + 30720)
#define OUT_TOTAL 232448

typedef _Float16 f16;
typedef _Float16 half2_t __attribute__((ext_vector_type(2)));
typedef _Float16 f16x8 __attribute__((ext_vector_type(8)));
typedef float f32x4 __attribute__((ext_vector_type(4)));

__device__ __forceinline__ float us2f(u16 v){
  return __uint_as_float(((u32)v) << 16);
}
__device__ __forceinline__ u16 f2bf(float f){
  __hip_bfloat16 h = __float2bfloat16(f);
  return *reinterpret_cast<u16*>(&h);
}
__device__ __forceinline__ float rcp_(float x){ return __builtin_amdgcn_rcpf(x); }
__device__ __forceinline__ float sigm(float x){
  return rcp_(1.f + __expf(-x));
}
__device__ __forceinline__ float tanh_(float x){
  float e = __expf(2.f*fabsf(x));
  float t = 1.f - 2.f*rcp_(e + 1.f);
  return copysignf(t, x);
}
__device__ __forceinline__ u32 pack2(float a, float b){
  half2_t h; h[0] = (f16)a; h[1] = (f16)b;
  return __builtin_bit_cast(u32, h);
}
__device__ __forceinline__ float fdot2_(u32 a, u32 b, float c){
  return __builtin_amdgcn_fdot2(__builtin_bit_cast(half2_t, a),
                                __builtin_bit_cast(half2_t, b), c, false);
}
__device__ __forceinline__ f16x8 bc16(uint4 v){ return __builtin_bit_cast(f16x8, v); }
__device__ __forceinline__ f32x4 mfma16(f16x8 a, f16x8 b, f32x4 c){
  return __builtin_amdgcn_mfma_f32_16x16x32_f16(a, b, c, 0, 0, 0);
}

// has is exactly {0,1}. f32 words: only 0x00000000 / 0x3F800000.
// bf16-pair words: 0x3F803F80 == (1.0,1.0) appears w.p. ~0.81 per pair.
__device__ __forceinline__ int detect_bf16(const u32* w){
  int f = 0;
  for (int i=0;i<256;i++) f |= (w[i] == 0x3F803F80u) ? 1 : 0;
  return f;
}

__global__ __launch_bounds__(256) void conv_in(
  const void* z, const void* dz, const void* has,
  const void* WihF, const void* WhhF, const void* bihF, const void* bhhF,
  const void* WihB, const void* WhhB, const void* bihB, const void* bhhB,
  const void* Wf_, const void* bf_, const void* Wb_, const void* bb_,
  const void* Wa, const void* ba, const void* Wc, const void* bc,
  const void* Wu, const void* bu, float* ws)
{
  const int isbf = detect_bf16((const u32*)has);
  if (blockIdx.x == 0 && threadIdx.x == 0) ws[OFF_FLAG] = (float)isbf;
  int idx = blockIdx.x*256 + threadIdx.x;
  if (idx >= CONV_TOTAL) return;
  const void* src; int loc;
  if      (idx < OFF_DZ  ){ src=z;    loc=idx-OFF_Z;    }
  else if (idx < OFF_HAS ){ src=dz;   loc=idx-OFF_DZ;   }
  else if (idx < OFF_WIHF){ src=has;  loc=idx-OFF_HAS;  }
  else if (idx < OFF_WHHF){ src=WihF; loc=idx-OFF_WIHF; }
  else if (idx < OFF_BIHF){ src=WhhF; loc=idx-OFF_WHHF; }
  else if (idx < OFF_BHHF){ src=bihF; loc=idx-OFF_BIHF; }
  else if (idx < OFF_WIHB){ src=bhhF; loc=idx-OFF_BHHF; }
  else if (idx < OFF_WHHB){ src=WihB; loc=idx-OFF_WIHB; }
  else if (idx < OFF_BIHB){ src=WhhB; loc=idx-OFF_WHHB; }
  else if (idx < OFF_BHHB){ src=bihB; loc=idx-OFF_BIHB; }
  else if (idx < OFF_WF  ){ src=bhhB; loc=idx-OFF_BHHB; }
  else if (idx < OFF_BF  ){ src=Wf_;  loc=idx-OFF_WF;   }
  else if (idx < OFF_WB  ){ src=bf_;  loc=idx-OFF_BF;   }
  else if (idx < OFF_BB  ){ src=Wb_;  loc=idx-OFF_WB;   }
  else if (idx < OFF_WA  ){ src=bb_;  loc=idx-OFF_BB;   }
  else if (idx < OFF_BA  ){ src=Wa;   loc=idx-OFF_WA;   }
  else if (idx < OFF_WC  ){ src=ba;   loc=idx-OFF_BA;   }
  else if (idx < OFF_BC  ){ src=Wc;   loc=idx-OFF_WC;   }
  else if (idx < OFF_WU  ){ src=bc;   loc=idx-OFF_BC;   }
  else if (idx < OFF_BU  ){ src=Wu;   loc=idx-OFF_WU;   }
  else                    { src=bu;   loc=idx-OFF_BU;   }
  float v = isbf ? us2f(((const u16*)src)[loc]) : ((const float*)src)[loc];
  ws[idx] = v;
}

// r17: 2-barrier step via broadcast-B MFMA matvec for phase 1.
//  - rho_t = tanh(Wch @ h_t + zdc): B-fragment = h_t broadcast (all ml
//    lanes read same 16B) -> D[16w+4q+reg][*] identical across columns;
//    lanes ml<4 add sZdc, tanh (2 trans/wave), write pad/hist/global.
//    Kills barriers P+A, the wave0 serial combine, sPart, wc entirely.
//  - consumer-row Bh fragments for groups 0/1 preloaded pre-R (reads only,
//    no cross-barrier accumulators -- r16's mistake); gate writes post-R.
//  - rho-dependent Dr/Dz halves computed once as Pr/Pz (MFMA C-in reuse).
// Step: [Bh preload + matvec + rho writes] -> R -> [Pr/Pz/Gn + groups] -> C.
__global__ __launch_bounds__(256, 4) void dir_kernel(const int* __restrict__ adj,
                                                     float* __restrict__ ws)
{
  const int tid = threadIdx.x;
  const int w   = tid >> 6;         // wave id (0..3) == row tile mt
  const int u   = tid & 63;         // lane
  const int ml  = u & 15;           // MFMA col (consumer slot)
  const int q   = u >> 4;           // MFMA quad
  const int bid = blockIdx.x;
  const int bwd = bid >> 9;
  const int b   = bid & 511;

  const float* Wih  = ws + (bwd ? OFF_WIHB : OFF_WIHF);
  const float* Whh  = ws + (bwd ? OFF_WHHB : OFF_WHHF);
  const float* bih  = ws + (bwd ? OFF_BIHB : OFF_BIHF);
  const float* bhh  = ws + (bwd ? OFF_BHHB : OFF_BHHF);
  const float* Wcat = ws + (bwd ? OFF_WB   : OFF_WF);
  const float* bcat = ws + (bwd ? OFF_BB   : OFF_BF);
  const float* zc   = ws + OFF_Z;
  const float* dzc  = ws + OFF_DZ;
  const float* hasc = ws + OFF_HAS;
  float* rho   = ws + (bwd ? OFF_RHOB : OFF_RHOF);  // [64][512][60]
  float* alpha = ws + (bwd ? OFF_ALB  : OFF_ALF);   // [512][60]

  __shared__ uint4 sH4[65][9];        // h rows, 144B stride; half63=1.0 (bias ch)
  __shared__ uint4 sRhoPad[8];        // rho_t halves; half63=1.0
  __shared__ uint4 sRhoHist[8][8];    // tail rho history; half63=1.0
  __shared__ float sZdc[NN][64];      // precomputed bias + z/dz contribution
  __shared__ u32 sZp[NN][5];
  __shared__ u32 sDZp[NN][5];
  __shared__ float sHas[NN];
  __shared__ u64 sRowM[NN];
  __shared__ u8 sConsL[NN][64];       // consumer lists (batch-independent)
  __shared__ int sConsCnt[NN];

  #define ROWB(I) ((char*)&sH4[(I)][0])
  const u32 BIASW = 0x3C000000u;      // halves {0, 1.0h}

  // ---- staging ----
  {
    if (tid < 64){
      u64 rowm = 0;
      for (int j=0;j<64;j++) rowm |= ((u64)(adj[tid*64+j]!=0))<<j;
      sRowM[tid] = rowm;
      sHas[tid] = hasc[b*NN + tid];
    }
    for (int idx=tid; idx<65*9; idx+=256){
      uint4 v = {0,0,0,0};
      if (idx % 9 == 7) v.w = BIASW;         // half63 = 1.0
      ((uint4*)sH4)[idx] = v;
    }
    if (tid < 8){ uint4 v={0,0,0,0}; if (tid==7) v.w = BIASW; sRhoPad[tid]=v; }
    if (tid < 64){ uint4 v={0,0,0,0}; if ((tid&7)==7) v.w = BIASW; ((uint4*)sRhoHist)[tid]=v; }
    for (int idx=tid; idx<NN*5; idx+=256){
      int n2=idx/5, p2=idx%5;
      sZp [n2][p2] = pack2(zc [(size_t)b*NN*SEX + n2*SEX + 2*p2],
                           zc [(size_t)b*NN*SEX + n2*SEX + 2*p2+1]);
      sDZp[n2][p2] = pack2(dzc[(size_t)b*NN*SEX + n2*SEX + 2*p2],
                           dzc[(size_t)b*NN*SEX + n2*SEX + 2*p2+1]);
    }
  }
  __syncthreads();
  if (tid < 64){
    u64 cm = 0;
    if (bwd) for (int i2=0;i2<64;i2++) cm |= ((sRowM[i2]>>tid)&1ULL)<<i2;
    u64 m = bwd ? cm : sRowM[tid];          // consumers of node tid
    int c = 0;
    while (m){ int i2 = (int)__builtin_ctzll(m); m &= m-1; sConsL[tid][c++] = (u8)i2; }
    sConsCnt[tid] = c;
  }
  // zdc precompute: sZdc[t][uu] = bcat[uu] + Wz.z_t + Wdz.dz_t (bias folded).
  // Wave tw handles t = tw, tw+4, ...; weights transient (staging only).
  {
    const int uu = tid & 63;
    const int tw = tid >> 6;
    if (uu < SP){
      u32 wz[10];
      #pragma unroll
      for (int p=0;p<10;p++)
        wz[p] = pack2(Wcat[uu*CATD + 60 + 2*p], Wcat[uu*CATD + 60 + 2*p + 1]);
      const float bb0 = bcat[uu];
      for (int t2=tw; t2<NN; t2+=4){
        float c = bb0;
        #pragma unroll
        for (int p=0;p<5;p++){
          c = fdot2_(wz[p],   sZp [t2][p], c);
          c = fdot2_(wz[5+p], sDZp[t2][p], c);
        }
        sZdc[t2][uu] = c;
      }
    }
  }

  // ---- A fragments (wave w owns mt = w): lane (q,ml) holds
  // A[row=16w+ml][K=32kt+8q+j] ----
  // Ar/Az: K<60 Whh, 64<=K<124 Wih, K==127 bias (bhh+bih).
  // Anh:   K<60 Whh_n, K==63 bias bhh_n.   Ani: K<60 Wih_n, K==63 bias bih_n.
  // Ac:    K<60 Wcat h-part (phase-1 matvec), else 0.
  f16x8 Ar[4], Az[4], Anh[2], Ani[2], Ac[2];
  {
    const int R = 16*w + ml;
    const bool rok = (R < SP);
    #pragma unroll
    for (int kt=0; kt<4; kt++){
      f16x8 vr, vz;
      #pragma unroll
      for (int j=0;j<8;j++){
        const int K = 32*kt + 8*q + j;
        float wr=0.f, wz2=0.f;
        if (rok){
          if (K < SP){ wr = Whh[R*SP+K]; wz2 = Whh[(60+R)*SP+K]; }
          else if (K >= 64 && K < 64+SP){ wr = Wih[R*SP+(K-64)]; wz2 = Wih[(60+R)*SP+(K-64)]; }
          else if (K == 127){ wr = bhh[R]+bih[R]; wz2 = bhh[60+R]+bih[60+R]; }
        }
        vr[j]=(f16)wr; vz[j]=(f16)wz2;
      }
      Ar[kt]=vr; Az[kt]=vz;
    }
    #pragma unroll
    for (int kt=0; kt<2; kt++){
      f16x8 vn, vi, vc;
      #pragma unroll
      for (int j=0;j<8;j++){
        const int K = 32*kt + 8*q + j;
        float wn=0.f, wi=0.f, wcv=0.f;
        if (rok){
          if (K < SP){ wn = Whh[(120+R)*SP+K]; wi = Wih[(120+R)*SP+K]; wcv = Wcat[R*CATD+K]; }
          else if (K == 63){ wn = bhh[120+R]; wi = bih[120+R]; }
        }
        vn[j]=(f16)wn; vi[j]=(f16)wi; vc[j]=(f16)wcv;
      }
      Anh[kt]=vn; Ani[kt]=vi; Ac[kt]=vc;
    }
  }
  __syncthreads();   // lists + zdc + LDS init visible

  // gates: in-register GRU gate math + h read-modify-write for row tile w,
  // consumer ci, slot column ml. Each wave touches only bytes [32w,32w+32)
  // of the row -> no cross-wave overlap.
  auto gates = [&](f32x4 Dr, f32x4 Dz, f32x4 Dn, f32x4 Gn,
                   int ci, bool wr, float bl){
    char* rp = ROWB(ci) + 32*w + 8*q;
    uint2 h2 = *(uint2*)rp;
    half2_t ha = __builtin_bit_cast(half2_t, h2.x);
    half2_t hb = __builtin_bit_cast(half2_t, h2.y);
    float hold[4] = { (float)ha[0], (float)ha[1], (float)hb[0], (float)hb[1] };
    float hw[4];
    #pragma unroll
    for (int reg=0;reg<4;reg++){
      float r_ = sigm(Dr[reg]);
      float zg = sigm(Dz[reg]);
      float nv = tanh_(Gn[reg] + r_*Dn[reg]);
      float hn_ = (1.f - zg)*nv + zg*hold[reg];
      hw[reg] = (bl != 0.f) ? hn_ : hold[reg];   // bl is exactly 0 or 1
    }
    if (wr && !(w==3 && q==3)){
      uint2 o; o.x = pack2(hw[0],hw[1]); o.y = pack2(hw[2],hw[3]);
      *(uint2*)rp = o;
    }
  };

  // full 11-MFMA pass (groups p>=2 [absent for this input] + tail)
  auto fullpass = [&](f16x8 Bh0, f16x8 Bh1, f16x8 Br0, f16x8 Br1,
                      f32x4 Gn, int ci, bool wr, float bl){
    f32x4 Dr={0,0,0,0}, Dz={0,0,0,0}, Dn={0,0,0,0};
    Dr = mfma16(Ar[0], Bh0, Dr); Dr = mfma16(Ar[1], Bh1, Dr);
    Dr = mfma16(Ar[2], Br0, Dr); Dr = mfma16(Ar[3], Br1, Dr);
    Dz = mfma16(Az[0], Bh0, Dz); Dz = mfma16(Az[1], Bh1, Dz);
    Dz = mfma16(Az[2], Br0, Dz); Dz = mfma16(Az[3], Br1, Dz);
    Dn = mfma16(Anh[0], Bh0, Dn); Dn = mfma16(Anh[1], Bh1, Dn);
    gates(Dr, Dz, Dn, Gn, ci, wr, bl);
  };

  // ---- 64 pipelined steps, 2 barriers each ----
  int t = bwd ? 63 : 0;
  const int dt = bwd ? -1 : 1;
  for (int s=0; s<64; s++, t+=dt){
    const float blendT = sHas[t];
    const int cnt = sConsCnt[t];
    const bool act = (blendT != 0.f) && (cnt > 0);   // block-uniform
    const bool g1  = act && (cnt > 16);

    // pre-R: consumer-row Bh preloads (reads only; R separates them from
    // this step's gate writes). No MFMAs on them yet (r16 lesson).
    int ci0 = 64, ci1 = 64;
    f16x8 Bh0g0={}, Bh1g0={}, Bh0g1={}, Bh1g1={};
    if (act){
      ci0 = (ml < cnt) ? (int)sConsL[t][ml] : 64;
      Bh0g0 = bc16(sH4[ci0][q]);
      Bh1g0 = bc16(sH4[ci0][4+q]);
      if (g1){
        ci1 = (16 + ml < cnt) ? (int)sConsL[t][16 + ml] : 64;
        Bh0g1 = bc16(sH4[ci1][q]);
        Bh1g1 = bc16(sH4[ci1][4+q]);
      }
    }

    // phase 1 matvec: rho_raw = Wch @ h_t via broadcast-B MFMA.
    // All ml lanes read the same h_t fragment -> every column of D holds
    // the same matvec; lane (q,ml) reg r = row 16w+4q+r.
    {
      const f16x8 Hb0 = bc16(sH4[t][q]);
      const f16x8 Hb1 = bc16(sH4[t][4+q]);
      f32x4 Rv = {0,0,0,0};
      Rv = mfma16(Ac[0], Hb0, Rv);
      Rv = mfma16(Ac[1], Hb1, Rv);
      const int row = 16*w + 4*q + ml;     // valid for ml<4
      if (ml < 4 && row < SP){
        float vv = Rv[0];
        vv = (ml==1) ? Rv[1] : vv;
        vv = (ml==2) ? Rv[2] : vv;
        vv = (ml==3) ? Rv[3] : vv;
        vv += sZdc[t][row];
        if (!bwd) vv = tanh_(vv);
        *(f16*)((char*)&sRhoPad[0] + 2*row) = (f16)vv;
        const int slot = bwd ? t : (t - (NN-OO));
        if (slot >= 0 && slot < 8)
          *(f16*)((char*)&sRhoHist[slot][0] + 2*row) = (f16)vv;
        rho[((size_t)t*BATCH + b)*SP + row] = vv;   // fire & forget
      }
    }
    __syncthreads();   // R: rho visible; pre-R h reads done before writes

    if (act){
      const f16x8 Br0 = bc16(sRhoPad[q]);
      const f16x8 Br1 = bc16(sRhoPad[4+q]);
      // consumer-independent accumulators (computed once, reused as C-in)
      f32x4 Gn={0,0,0,0};
      Gn = mfma16(Ani[0], Br0, Gn); Gn = mfma16(Ani[1], Br1, Gn);
      f32x4 Pr={0,0,0,0};
      Pr = mfma16(Ar[2], Br0, Pr); Pr = mfma16(Ar[3], Br1, Pr);
      f32x4 Pz={0,0,0,0};
      Pz = mfma16(Az[2], Br0, Pz); Pz = mfma16(Az[3], Br1, Pz);

      { // group 0
        f32x4 Dr=Pr, Dz=Pz, Dn={0,0,0,0};
        Dr = mfma16(Ar[0], Bh0g0, Dr); Dr = mfma16(Ar[1], Bh1g0, Dr);
        Dz = mfma16(Az[0], Bh0g0, Dz); Dz = mfma16(Az[1], Bh1g0, Dz);
        Dn = mfma16(Anh[0], Bh0g0, Dn); Dn = mfma16(Anh[1], Bh1g0, Dn);
        gates(Dr, Dz, Dn, Gn, ci0, ml < cnt, 1.0f);
      }
      if (g1){
        f32x4 Dr=Pr, Dz=Pz, Dn={0,0,0,0};
        Dr = mfma16(Ar[0], Bh0g1, Dr); Dr = mfma16(Ar[1], Bh1g1, Dr);
        Dz = mfma16(Az[0], Bh0g1, Dz); Dz = mfma16(Az[1], Bh1g1, Dz);
        Dn = mfma16(Anh[0], Bh0g1, Dn); Dn = mfma16(Anh[1], Bh1g1, Dn);
        gates(Dr, Dz, Dn, Gn, ci1, 16 + ml < cnt, 1.0f);
      }
      // groups p>=2 (absent for this input, kept for generality)
      for (int p=2; 16*p < cnt; p++){
        const int idxp = 16*p + ml;
        const int ci = (idxp < cnt) ? (int)sConsL[t][idxp] : 64;
        const f16x8 Bh0 = bc16(sH4[ci][q]);
        const f16x8 Bh1 = bc16(sH4[ci][4+q]);
        fullpass(Bh0, Bh1, Br0, Br1, Gn, ci, idxp < cnt, 1.0f);
      }
    }
    __syncthreads();   // C: h writes visible to next step's reads
  }

  // ---- alpha tail: 8 GRU steps on scratch row 64 ----
  for (int s2=0; s2<8; s2++){
    const int i = bwd ? (7 - s2) : (NN - OO + s2);
    const int slot = bwd ? i : (i - (NN-OO));
    const f16x8 Th0 = bc16(sH4[64][q]);
    const f16x8 Th1 = bc16(sH4[64][4+q]);
    const f16x8 Tr0 = bc16(sRhoHist[slot][q]);
    const f16x8 Tr1 = bc16(sRhoHist[slot][4+q]);
    f32x4 Gt={0,0,0,0};
    Gt = mfma16(Ani[0], Tr0, Gt);
    Gt = mfma16(Ani[1], Tr1, Gt);
    __syncthreads();   // all waves' row-64 reads done before writes
    fullpass(Th0, Th1, Tr0, Tr1, Gt, 64, ml==0, sHas[i]);
    __syncthreads();   // writes visible to next tail step
  }
  if (tid < SP) alpha[(size_t)b*SP + tid] = (float)*(const f16*)(ROWB(64) + 2*tid);
  #undef ROWB
}

// One block per batch element: psi + softmaxes, omega, value -> d_out directly.
__global__ __launch_bounds__(256, 1) void head_kernel(float* __restrict__ ws,
                                                      void* __restrict__ outp)
{
  const int b = blockIdx.x;
  const int tid = threadIdx.x;
  const int isbf = (ws[OFF_FLAG] != 0.f);
  const float* hasc   = ws + OFF_HAS;
  const float* WaC    = ws + OFF_WA;
  const float* baC    = ws + OFF_BA;
  const float* WcC    = ws + OFF_WC;
  const float* bcC    = ws + OFF_BC;
  const float* WuC    = ws + OFF_WU;
  const float* buC    = ws + OFF_BU;
  const float* rhoF   = ws + OFF_RHOF;
  const float* rhoB   = ws + OFF_RHOB;
  const float* alphaF = ws + OFF_ALF;
  const float* alphaB = ws + OFF_ALB;

  __shared__ float sF[NN][121];
  __shared__ float sAB[120];
  __shared__ float sWu[NR*120];
  __shared__ float sHasR[NN];
  __shared__ float sPsi[NR][NN];
  __shared__ float sRed[NR][2];
  __shared__ float sOm[NA];

  auto wout = [&](int idx, float v){
    if (isbf) ((u16*)outp)[idx] = f2bf(v);
    else      ((float*)outp)[idx] = v;
  };

  for (int idx=tid; idx<NN*SP; idx+=256){
    int n = idx/SP, s = idx%SP;
    sF[n][s]    = rhoF[((size_t)n*BATCH + b)*SP + s];
    sF[n][60+s] = rhoB[((size_t)n*BATCH + b)*SP + s];
  }
  for (int idx=tid; idx<120; idx+=256)
    sAB[idx] = (idx<60) ? alphaF[(size_t)b*SP + idx] : alphaB[(size_t)b*SP + idx-60];
  for (int idx=tid; idx<NR*120; idx+=256) sWu[idx] = WuC[idx];
  for (int idx=tid; idx<NN; idx+=256) sHasR[idx] = hasc[b*NN + idx];
  __syncthreads();

  for (int idx=tid; idx<NR*NN; idx+=256){
    int r = idx/NN, n = idx%NN;
    float acc = buC[r];
    for (int s=0;s<120;s++) acc += sF[n][s]*sWu[r*120+s];
    sPsi[r][n] = (sHasR[n] != 0.f) ? acc : -60.f;
  }
  if (tid >= 64 && tid < 64+NA){
    int a = tid - 64;
    float acc = baC[a];
    for (int s=0;s<120;s++) acc += sAB[s]*WaC[a*120+s];
    sOm[a] = acc;
  }
  if (tid == 70){
    float acc = bcC[0];
    for (int s=0;s<120;s++) acc += sAB[s]*WcC[s];
    wout(2560 + BATCH*NR*NN + b, acc);                 // value
  }
  __syncthreads();

  if (tid < NR){
    float m = -1e30f;
    for (int n=0;n<NN;n++) m = fmaxf(m, sPsi[tid][n]);
    float ssum = 0.f;
    for (int n=0;n<NN;n++) ssum += __expf(sPsi[tid][n]-m);
    sRed[tid][0] = m; sRed[tid][1] = 1.f/ssum;
  }
  if (tid == 8){
    float m = -1e30f;
    for (int a=0;a<NA;a++) m = fmaxf(m, sOm[a]);
    float e[NA]; float ssum = 0.f;
    for (int a=0;a<NA;a++){ e[a] = __expf(sOm[a]-m); ssum += e[a]; }
    for (int a=0;a<NA;a++) wout(b*NA + a, e[a]/ssum);  // instr_prob
  }
  __syncthreads();

  for (int idx=tid; idx<NR*NN; idx+=256){
    int r = idx/NN, n = idx%NN;
    float v = __expf(sPsi[r][n]-sRed[r][0]) * sRed[r][1];
    wout(2560 + (size_t)b*NR*NN + idx, v);             // role_prob
  }
}

extern "C" void kernel_launch(void* const* d_in, const int* in_sizes, int n_in,
                              void* d_out, int out_size, void* d_ws, size_t ws_size,
                              hipStream_t stream)
{
  const int* adj = (const int*)d_in[3];
  float* ws = (float*)d_ws;

  conv_in<<<(CONV_TOTAL+255)/256, 256, 0, stream>>>(
      d_in[0], d_in[1], d_in[2],
      d_in[4], d_in[5], d_in[6], d_in[7],
      d_in[8], d_in[9], d_in[10], d_in[11],
      d_in[12], d_in[13], d_in[14], d_in[15],
      d_in[16], d_in[17], d_in[18], d_in[19],
      d_in[20], d_in[21], ws);

  dir_kernel<<<1024, 256, 0, stream>>>(adj, ws);

  head_kernel<<<512, 256, 0, stream>>>(ws, d_out);
}

// Round 7
// 256.911 us; speedup vs baseline: 1.1343x; 1.0622x over previous
//
#include <hip/hip_runtime.h>
#include <hip/hip_bf16.h>

#define NN 64
#define BATCH 512
#define SP 60
#define SG 180
#define SEX 10
#define CATD 80
#define NA 5
#define NR 7
#define OO 8
#define II 8

typedef unsigned long long u64;
typedef unsigned short u16;
typedef unsigned int u32;
typedef unsigned char u8;

// ---- workspace layout (float offsets) ----
#define OFF_Z     0
#define OFF_DZ    327680
#define OFF_HAS   655360
#define OFF_WIHF  688128
#define OFF_WHHF  698928
#define OFF_BIHF  709728
#define OFF_BHHF  709908
#define OFF_WIHB  710088
#define OFF_WHHB  720888
#define OFF_BIHB  731688
#define OFF_BHHB  731868
#define OFF_WF    732048
#define OFF_BF    736848
#define OFF_WB    736908
#define OFF_BB    741708
#define OFF_WA    741768
#define OFF_BA    742368
#define OFF_WC    742373
#define OFF_BC    742493
#define OFF_WU    742494
#define OFF_BU    743334
#define CONV_TOTAL 743341
#define OFF_FLAG  743342
#define OFF_RHOF  743344
#define OFF_RHOB  (OFF_RHOF + 1966080)
#define OFF_ALF   (OFF_RHOB + 1966080)
#define OFF_ALB   (OFF_ALF + 30720)
#define OUT_TOTAL 232448

typedef _Float16 f16;
typedef _Float16 half2_t __attribute__((ext_vector_type(2)));
typedef _Float16 f16x8 __attribute__((ext_vector_type(8)));
typedef float f32x4 __attribute__((ext_vector_type(4)));

__device__ __forceinline__ float us2f(u16 v){
  return __uint_as_float(((u32)v) << 16);
}
__device__ __forceinline__ u16 f2bf(float f){
  __hip_bfloat16 h = __float2bfloat16(f);
  return *reinterpret_cast<u16*>(&h);
}
__device__ __forceinline__ float rcp_(float x){ return __builtin_amdgcn_rcpf(x); }
__device__ __forceinline__ float sigm(float x){
  return rcp_(1.f + __expf(-x));
}
__device__ __forceinline__ float tanh_(float x){
  float e = __expf(2.f*fabsf(x));
  float t = 1.f - 2.f*rcp_(e + 1.f);
  return copysignf(t, x);
}
__device__ __forceinline__ u32 pack2(float a, float b){
  half2_t h; h[0] = (f16)a; h[1] = (f16)b;
  return __builtin_bit_cast(u32, h);
}
__device__ __forceinline__ float fdot2_(u32 a, u32 b, float c){
  return __builtin_amdgcn_fdot2(__builtin_bit_cast(half2_t, a),
                                __builtin_bit_cast(half2_t, b), c, false);
}
__device__ __forceinline__ f16x8 bc16(uint4 v){ return __builtin_bit_cast(f16x8, v); }
__device__ __forceinline__ f32x4 mfma16(f16x8 a, f16x8 b, f32x4 c){
  return __builtin_amdgcn_mfma_f32_16x16x32_f16(a, b, c, 0, 0, 0);
}

// has is exactly {0,1}. f32 words: only 0x00000000 / 0x3F800000.
// bf16-pair words: 0x3F803F80 == (1.0,1.0) appears w.p. ~0.81 per pair.
// r18: cooperative detect — wave 0 scans the 1KB (4 words/lane) + ballot,
// broadcast via LDS. Replaces the per-thread 256-iteration scan that cost
// ~190M redundant loads grid-wide.
__global__ __launch_bounds__(256) void conv_in(
  const void* z, const void* dz, const void* has,
  const void* WihF, const void* WhhF, const void* bihF, const void* bhhF,
  const void* WihB, const void* WhhB, const void* bihB, const void* bhhB,
  const void* Wf_, const void* bf_, const void* Wb_, const void* bb_,
  const void* Wa, const void* ba, const void* Wc, const void* bc,
  const void* Wu, const void* bu, float* ws)
{
  __shared__ int sIsBf;
  const int tid = threadIdx.x;
  if (tid < 64){
    const u32* w = (const u32*)has;
    int f = 0;
    #pragma unroll
    for (int k=0;k<4;k++) f |= (w[tid*4 + k] == 0x3F803F80u) ? 1 : 0;
    u64 m = __ballot(f != 0);
    if (tid == 0) sIsBf = (m != 0ULL) ? 1 : 0;
  }
  __syncthreads();
  const int isbf = sIsBf;
  if (blockIdx.x == 0 && tid == 0) ws[OFF_FLAG] = (float)isbf;
  int idx = blockIdx.x*256 + tid;
  if (idx >= CONV_TOTAL) return;
  const void* src; int loc;
  if      (idx < OFF_DZ  ){ src=z;    loc=idx-OFF_Z;    }
  else if (idx < OFF_HAS ){ src=dz;   loc=idx-OFF_DZ;   }
  else if (idx < OFF_WIHF){ src=has;  loc=idx-OFF_HAS;  }
  else if (idx < OFF_WHHF){ src=WihF; loc=idx-OFF_WIHF; }
  else if (idx < OFF_BIHF){ src=WhhF; loc=idx-OFF_WHHF; }
  else if (idx < OFF_BHHF){ src=bihF; loc=idx-OFF_BIHF; }
  else if (idx < OFF_WIHB){ src=bhhF; loc=idx-OFF_BHHF; }
  else if (idx < OFF_WHHB){ src=WihB; loc=idx-OFF_WIHB; }
  else if (idx < OFF_BIHB){ src=WhhB; loc=idx-OFF_WHHB; }
  else if (idx < OFF_BHHB){ src=bihB; loc=idx-OFF_BIHB; }
  else if (idx < OFF_WF  ){ src=bhhB; loc=idx-OFF_BHHB; }
  else if (idx < OFF_BF  ){ src=Wf_;  loc=idx-OFF_WF;   }
  else if (idx < OFF_WB  ){ src=bf_;  loc=idx-OFF_BF;   }
  else if (idx < OFF_BB  ){ src=Wb_;  loc=idx-OFF_WB;   }
  else if (idx < OFF_WA  ){ src=bb_;  loc=idx-OFF_BB;   }
  else if (idx < OFF_BA  ){ src=Wa;   loc=idx-OFF_WA;   }
  else if (idx < OFF_WC  ){ src=ba;   loc=idx-OFF_BA;   }
  else if (idx < OFF_BC  ){ src=Wc;   loc=idx-OFF_WC;   }
  else if (idx < OFF_WU  ){ src=bc;   loc=idx-OFF_BC;   }
  else if (idx < OFF_BU  ){ src=Wu;   loc=idx-OFF_WU;   }
  else                    { src=bu;   loc=idx-OFF_BU;   }
  float v = isbf ? us2f(((const u16*)src)[loc]) : ((const float*)src)[loc];
  ws[idx] = v;
}

// r17 (unchanged): 2-barrier step via broadcast-B MFMA matvec for phase 1.
//  - rho_t = tanh(Wch @ h_t + zdc): B-fragment = h_t broadcast (all ml
//    lanes read same 16B) -> D[16w+4q+reg][*] identical across columns;
//    lanes ml<4 add sZdc, tanh (2 trans/wave), write pad/hist/global.
//  - consumer-row Bh fragments for groups 0/1 preloaded pre-R (reads only).
//  - rho-dependent Dr/Dz halves computed once as Pr/Pz (MFMA C-in reuse).
// Step: [Bh preload + matvec + rho writes] -> R -> [Pr/Pz/Gn + groups] -> C.
__global__ __launch_bounds__(256, 4) void dir_kernel(const int* __restrict__ adj,
                                                     float* __restrict__ ws)
{
  const int tid = threadIdx.x;
  const int w   = tid >> 6;         // wave id (0..3) == row tile mt
  const int u   = tid & 63;         // lane
  const int ml  = u & 15;           // MFMA col (consumer slot)
  const int q   = u >> 4;           // MFMA quad
  const int bid = blockIdx.x;
  const int bwd = bid >> 9;
  const int b   = bid & 511;

  const float* Wih  = ws + (bwd ? OFF_WIHB : OFF_WIHF);
  const float* Whh  = ws + (bwd ? OFF_WHHB : OFF_WHHF);
  const float* bih  = ws + (bwd ? OFF_BIHB : OFF_BIHF);
  const float* bhh  = ws + (bwd ? OFF_BHHB : OFF_BHHF);
  const float* Wcat = ws + (bwd ? OFF_WB   : OFF_WF);
  const float* bcat = ws + (bwd ? OFF_BB   : OFF_BF);
  const float* zc   = ws + OFF_Z;
  const float* dzc  = ws + OFF_DZ;
  const float* hasc = ws + OFF_HAS;
  float* rho   = ws + (bwd ? OFF_RHOB : OFF_RHOF);  // [64][512][60]
  float* alpha = ws + (bwd ? OFF_ALB  : OFF_ALF);   // [512][60]

  __shared__ uint4 sH4[65][9];        // h rows, 144B stride; half63=1.0 (bias ch)
  __shared__ uint4 sRhoPad[8];        // rho_t halves; half63=1.0
  __shared__ uint4 sRhoHist[8][8];    // tail rho history; half63=1.0
  __shared__ float sZdc[NN][64];      // precomputed bias + z/dz contribution
  __shared__ u32 sZp[NN][5];
  __shared__ u32 sDZp[NN][5];
  __shared__ float sHas[NN];
  __shared__ u64 sRowM[NN];
  __shared__ u8 sConsL[NN][64];       // consumer lists (batch-independent)
  __shared__ int sConsCnt[NN];

  #define ROWB(I) ((char*)&sH4[(I)][0])
  const u32 BIASW = 0x3C000000u;      // halves {0, 1.0h}

  // ---- staging ----
  {
    if (tid < 64){
      u64 rowm = 0;
      for (int j=0;j<64;j++) rowm |= ((u64)(adj[tid*64+j]!=0))<<j;
      sRowM[tid] = rowm;
      sHas[tid] = hasc[b*NN + tid];
    }
    for (int idx=tid; idx<65*9; idx+=256){
      uint4 v = {0,0,0,0};
      if (idx % 9 == 7) v.w = BIASW;         // half63 = 1.0
      ((uint4*)sH4)[idx] = v;
    }
    if (tid < 8){ uint4 v={0,0,0,0}; if (tid==7) v.w = BIASW; sRhoPad[tid]=v; }
    if (tid < 64){ uint4 v={0,0,0,0}; if ((tid&7)==7) v.w = BIASW; ((uint4*)sRhoHist)[tid]=v; }
    for (int idx=tid; idx<NN*5; idx+=256){
      int n2=idx/5, p2=idx%5;
      sZp [n2][p2] = pack2(zc [(size_t)b*NN*SEX + n2*SEX + 2*p2],
                           zc [(size_t)b*NN*SEX + n2*SEX + 2*p2+1]);
      sDZp[n2][p2] = pack2(dzc[(size_t)b*NN*SEX + n2*SEX + 2*p2],
                           dzc[(size_t)b*NN*SEX + n2*SEX + 2*p2+1]);
    }
  }
  __syncthreads();
  if (tid < 64){
    u64 cm = 0;
    if (bwd) for (int i2=0;i2<64;i2++) cm |= ((sRowM[i2]>>tid)&1ULL)<<i2;
    u64 m = bwd ? cm : sRowM[tid];          // consumers of node tid
    int c = 0;
    while (m){ int i2 = (int)__builtin_ctzll(m); m &= m-1; sConsL[tid][c++] = (u8)i2; }
    sConsCnt[tid] = c;
  }
  // zdc precompute: sZdc[t][uu] = bcat[uu] + Wz.z_t + Wdz.dz_t (bias folded).
  // Wave tw handles t = tw, tw+4, ...; weights transient (staging only).
  {
    const int uu = tid & 63;
    const int tw = tid >> 6;
    if (uu < SP){
      u32 wz[10];
      #pragma unroll
      for (int p=0;p<10;p++)
        wz[p] = pack2(Wcat[uu*CATD + 60 + 2*p], Wcat[uu*CATD + 60 + 2*p + 1]);
      const float bb0 = bcat[uu];
      for (int t2=tw; t2<NN; t2+=4){
        float c = bb0;
        #pragma unroll
        for (int p=0;p<5;p++){
          c = fdot2_(wz[p],   sZp [t2][p], c);
          c = fdot2_(wz[5+p], sDZp[t2][p], c);
        }
        sZdc[t2][uu] = c;
      }
    }
  }

  // ---- A fragments (wave w owns mt = w): lane (q,ml) holds
  // A[row=16w+ml][K=32kt+8q+j] ----
  // Ar/Az: K<60 Whh, 64<=K<124 Wih, K==127 bias (bhh+bih).
  // Anh:   K<60 Whh_n, K==63 bias bhh_n.   Ani: K<60 Wih_n, K==63 bias bih_n.
  // Ac:    K<60 Wcat h-part (phase-1 matvec), else 0.
  f16x8 Ar[4], Az[4], Anh[2], Ani[2], Ac[2];
  {
    const int R = 16*w + ml;
    const bool rok = (R < SP);
    #pragma unroll
    for (int kt=0; kt<4; kt++){
      f16x8 vr, vz;
      #pragma unroll
      for (int j=0;j<8;j++){
        const int K = 32*kt + 8*q + j;
        float wr=0.f, wz2=0.f;
        if (rok){
          if (K < SP){ wr = Whh[R*SP+K]; wz2 = Whh[(60+R)*SP+K]; }
          else if (K >= 64 && K < 64+SP){ wr = Wih[R*SP+(K-64)]; wz2 = Wih[(60+R)*SP+(K-64)]; }
          else if (K == 127){ wr = bhh[R]+bih[R]; wz2 = bhh[60+R]+bih[60+R]; }
        }
        vr[j]=(f16)wr; vz[j]=(f16)wz2;
      }
      Ar[kt]=vr; Az[kt]=vz;
    }
    #pragma unroll
    for (int kt=0; kt<2; kt++){
      f16x8 vn, vi, vc;
      #pragma unroll
      for (int j=0;j<8;j++){
        const int K = 32*kt + 8*q + j;
        float wn=0.f, wi=0.f, wcv=0.f;
        if (rok){
          if (K < SP){ wn = Whh[(120+R)*SP+K]; wi = Wih[(120+R)*SP+K]; wcv = Wcat[R*CATD+K]; }
          else if (K == 63){ wn = bhh[120+R]; wi = bih[120+R]; }
        }
        vn[j]=(f16)wn; vi[j]=(f16)wi; vc[j]=(f16)wcv;
      }
      Anh[kt]=vn; Ani[kt]=vi; Ac[kt]=vc;
    }
  }
  __syncthreads();   // lists + zdc + LDS init visible

  // gates: in-register GRU gate math + h read-modify-write for row tile w,
  // consumer ci, slot column ml. Each wave touches only bytes [32w,32w+32)
  // of the row -> no cross-wave overlap.
  auto gates = [&](f32x4 Dr, f32x4 Dz, f32x4 Dn, f32x4 Gn,
                   int ci, bool wr, float bl){
    char* rp = ROWB(ci) + 32*w + 8*q;
    uint2 h2 = *(uint2*)rp;
    half2_t ha = __builtin_bit_cast(half2_t, h2.x);
    half2_t hb = __builtin_bit_cast(half2_t, h2.y);
    float hold[4] = { (float)ha[0], (float)ha[1], (float)hb[0], (float)hb[1] };
    float hw[4];
    #pragma unroll
    for (int reg=0;reg<4;reg++){
      float r_ = sigm(Dr[reg]);
      float zg = sigm(Dz[reg]);
      float nv = tanh_(Gn[reg] + r_*Dn[reg]);
      float hn_ = (1.f - zg)*nv + zg*hold[reg];
      hw[reg] = (bl != 0.f) ? hn_ : hold[reg];   // bl is exactly 0 or 1
    }
    if (wr && !(w==3 && q==3)){
      uint2 o; o.x = pack2(hw[0],hw[1]); o.y = pack2(hw[2],hw[3]);
      *(uint2*)rp = o;
    }
  };

  // full 11-MFMA pass (groups p>=2 [absent for this input] + tail)
  auto fullpass = [&](f16x8 Bh0, f16x8 Bh1, f16x8 Br0, f16x8 Br1,
                      f32x4 Gn, int ci, bool wr, float bl){
    f32x4 Dr={0,0,0,0}, Dz={0,0,0,0}, Dn={0,0,0,0};
    Dr = mfma16(Ar[0], Bh0, Dr); Dr = mfma16(Ar[1], Bh1, Dr);
    Dr = mfma16(Ar[2], Br0, Dr); Dr = mfma16(Ar[3], Br1, Dr);
    Dz = mfma16(Az[0], Bh0, Dz); Dz = mfma16(Az[1], Bh1, Dz);
    Dz = mfma16(Az[2], Br0, Dz); Dz = mfma16(Az[3], Br1, Dz);
    Dn = mfma16(Anh[0], Bh0, Dn); Dn = mfma16(Anh[1], Bh1, Dn);
    gates(Dr, Dz, Dn, Gn, ci, wr, bl);
  };

  // ---- 64 pipelined steps, 2 barriers each ----
  int t = bwd ? 63 : 0;
  const int dt = bwd ? -1 : 1;
  for (int s=0; s<64; s++, t+=dt){
    const float blendT = sHas[t];
    const int cnt = sConsCnt[t];
    const bool act = (blendT != 0.f) && (cnt > 0);   // block-uniform
    const bool g1  = act && (cnt > 16);

    // pre-R: consumer-row Bh preloads (reads only; R separates them from
    // this step's gate writes).
    int ci0 = 64, ci1 = 64;
    f16x8 Bh0g0={}, Bh1g0={}, Bh0g1={}, Bh1g1={};
    if (act){
      ci0 = (ml < cnt) ? (int)sConsL[t][ml] : 64;
      Bh0g0 = bc16(sH4[ci0][q]);
      Bh1g0 = bc16(sH4[ci0][4+q]);
      if (g1){
        ci1 = (16 + ml < cnt) ? (int)sConsL[t][16 + ml] : 64;
        Bh0g1 = bc16(sH4[ci1][q]);
        Bh1g1 = bc16(sH4[ci1][4+q]);
      }
    }

    // phase 1 matvec: rho_raw = Wch @ h_t via broadcast-B MFMA.
    {
      const f16x8 Hb0 = bc16(sH4[t][q]);
      const f16x8 Hb1 = bc16(sH4[t][4+q]);
      f32x4 Rv = {0,0,0,0};
      Rv = mfma16(Ac[0], Hb0, Rv);
      Rv = mfma16(Ac[1], Hb1, Rv);
      const int row = 16*w + 4*q + ml;     // valid for ml<4
      if (ml < 4 && row < SP){
        float vv = Rv[0];
        vv = (ml==1) ? Rv[1] : vv;
        vv = (ml==2) ? Rv[2] : vv;
        vv = (ml==3) ? Rv[3] : vv;
        vv += sZdc[t][row];
        if (!bwd) vv = tanh_(vv);
        *(f16*)((char*)&sRhoPad[0] + 2*row) = (f16)vv;
        const int slot = bwd ? t : (t - (NN-OO));
        if (slot >= 0 && slot < 8)
          *(f16*)((char*)&sRhoHist[slot][0] + 2*row) = (f16)vv;
        rho[((size_t)t*BATCH + b)*SP + row] = vv;   // fire & forget
      }
    }
    __syncthreads();   // R: rho visible; pre-R h reads done before writes

    if (act){
      const f16x8 Br0 = bc16(sRhoPad[q]);
      const f16x8 Br1 = bc16(sRhoPad[4+q]);
      // consumer-independent accumulators (computed once, reused as C-in)
      f32x4 Gn={0,0,0,0};
      Gn = mfma16(Ani[0], Br0, Gn); Gn = mfma16(Ani[1], Br1, Gn);
      f32x4 Pr={0,0,0,0};
      Pr = mfma16(Ar[2], Br0, Pr); Pr = mfma16(Ar[3], Br1, Pr);
      f32x4 Pz={0,0,0,0};
      Pz = mfma16(Az[2], Br0, Pz); Pz = mfma16(Az[3], Br1, Pz);

      { // group 0
        f32x4 Dr=Pr, Dz=Pz, Dn={0,0,0,0};
        Dr = mfma16(Ar[0], Bh0g0, Dr); Dr = mfma16(Ar[1], Bh1g0, Dr);
        Dz = mfma16(Az[0], Bh0g0, Dz); Dz = mfma16(Az[1], Bh1g0, Dz);
        Dn = mfma16(Anh[0], Bh0g0, Dn); Dn = mfma16(Anh[1], Bh1g0, Dn);
        gates(Dr, Dz, Dn, Gn, ci0, ml < cnt, 1.0f);
      }
      if (g1){
        f32x4 Dr=Pr, Dz=Pz, Dn={0,0,0,0};
        Dr = mfma16(Ar[0], Bh0g1, Dr); Dr = mfma16(Ar[1], Bh1g1, Dr);
        Dz = mfma16(Az[0], Bh0g1, Dz); Dz = mfma16(Az[1], Bh1g1, Dz);
        Dn = mfma16(Anh[0], Bh0g1, Dn); Dn = mfma16(Anh[1], Bh1g1, Dn);
        gates(Dr, Dz, Dn, Gn, ci1, 16 + ml < cnt, 1.0f);
      }
      // groups p>=2 (absent for this input, kept for generality)
      for (int p=2; 16*p < cnt; p++){
        const int idxp = 16*p + ml;
        const int ci = (idxp < cnt) ? (int)sConsL[t][idxp] : 64;
        const f16x8 Bh0 = bc16(sH4[ci][q]);
        const f16x8 Bh1 = bc16(sH4[ci][4+q]);
        fullpass(Bh0, Bh1, Br0, Br1, Gn, ci, idxp < cnt, 1.0f);
      }
    }
    __syncthreads();   // C: h writes visible to next step's reads
  }

  // ---- alpha tail: 8 GRU steps on scratch row 64 ----
  for (int s2=0; s2<8; s2++){
    const int i = bwd ? (7 - s2) : (NN - OO + s2);
    const int slot = bwd ? i : (i - (NN-OO));
    const f16x8 Th0 = bc16(sH4[64][q]);
    const f16x8 Th1 = bc16(sH4[64][4+q]);
    const f16x8 Tr0 = bc16(sRhoHist[slot][q]);
    const f16x8 Tr1 = bc16(sRhoHist[slot][4+q]);
    f32x4 Gt={0,0,0,0};
    Gt = mfma16(Ani[0], Tr0, Gt);
    Gt = mfma16(Ani[1], Tr1, Gt);
    __syncthreads();   // all waves' row-64 reads done before writes
    fullpass(Th0, Th1, Tr0, Tr1, Gt, 64, ml==0, sHas[i]);
    __syncthreads();   // writes visible to next tail step
  }
  if (tid < SP) alpha[(size_t)b*SP + tid] = (float)*(const f16*)(ROWB(64) + 2*tid);
  #undef ROWB
}

// One block per batch element: psi + softmaxes, omega, value -> d_out directly.
// r18: float2 LDS reads for psi (sF stride 122, 8B-aligned); softmax
// parallelized to 7x32 lanes with shfl_xor; outputs written in the same
// phase (drops sRed + one barrier + the second psi pass).
__global__ __launch_bounds__(256, 1) void head_kernel(float* __restrict__ ws,
                                                      void* __restrict__ outp)
{
  const int b = blockIdx.x;
  const int tid = threadIdx.x;
  const int isbf = (ws[OFF_FLAG] != 0.f);
  const float* hasc   = ws + OFF_HAS;
  const float* WaC    = ws + OFF_WA;
  const float* baC    = ws + OFF_BA;
  const float* WcC    = ws + OFF_WC;
  const float* bcC    = ws + OFF_BC;
  const float* WuC    = ws + OFF_WU;
  const float* buC    = ws + OFF_BU;
  const float* rhoF   = ws + OFF_RHOF;
  const float* rhoB   = ws + OFF_RHOB;
  const float* alphaF = ws + OFF_ALF;
  const float* alphaB = ws + OFF_ALB;

  __shared__ float sF[NN][122];    // 488B stride: float2-aligned, 2-way banks
  __shared__ float sAB[120];
  __shared__ float sWu[NR*120];
  __shared__ float sHasR[NN];
  __shared__ float sPsi[NR][NN];
  __shared__ float sOm[NA];

  auto wout = [&](int idx, float v){
    if (isbf) ((u16*)outp)[idx] = f2bf(v);
    else      ((float*)outp)[idx] = v;
  };

  for (int idx=tid; idx<NN*SP; idx+=256){
    int n = idx/SP, s = idx%SP;
    sF[n][s]    = rhoF[((size_t)n*BATCH + b)*SP + s];
    sF[n][60+s] = rhoB[((size_t)n*BATCH + b)*SP + s];
  }
  for (int idx=tid; idx<120; idx+=256)
    sAB[idx] = (idx<60) ? alphaF[(size_t)b*SP + idx] : alphaB[(size_t)b*SP + idx-60];
  for (int idx=tid; idx<NR*120; idx+=256) sWu[idx] = WuC[idx];
  for (int idx=tid; idx<NN; idx+=256) sHasR[idx] = hasc[b*NN + idx];
  __syncthreads();

  // psi: r = idx/64 wave-uniform (sWu reads broadcast), n = lane
  for (int idx=tid; idx<NR*NN; idx+=256){
    int r = idx/NN, n = idx%NN;
    const float2* fn = (const float2*)&sF[n][0];
    const float2* wr = (const float2*)&sWu[r*120];
    float acc = buC[r];
    #pragma unroll 6
    for (int s2=0;s2<60;s2++){
      float2 a = fn[s2], c = wr[s2];
      acc += a.x*c.x;
      acc += a.y*c.y;
    }
    sPsi[r][n] = (sHasR[n] != 0.f) ? acc : -60.f;
  }
  if (tid >= 64 && tid < 64+NA){
    int a = tid - 64;
    float acc = baC[a];
    for (int s=0;s<120;s++) acc += sAB[s]*WaC[a*120+s];
    sOm[a] = acc;
  }
  if (tid == 70){
    float acc = bcC[0];
    for (int s=0;s<120;s++) acc += sAB[s]*WcC[s];
    wout(2560 + BATCH*NR*NN + b, acc);                 // value
  }
  __syncthreads();

  // role softmax: row r handled by aligned 32-lane group (tid = r*32+l);
  // each lane owns n = l and n = l+32; shfl_xor masks <32 stay in-group.
  if (tid < NR*32){
    const int r = tid >> 5, l = tid & 31;
    float v0 = sPsi[r][l], v1 = sPsi[r][l+32];
    float m = fmaxf(v0, v1);
    #pragma unroll
    for (int o=16;o>0;o>>=1) m = fmaxf(m, __shfl_xor(m, o, 64));
    float e0 = __expf(v0 - m), e1 = __expf(v1 - m);
    float ssum = e0 + e1;
    #pragma unroll
    for (int o=16;o>0;o>>=1) ssum += __shfl_xor(ssum, o, 64);
    float rinv = 1.f/ssum;
    wout(2560 + (size_t)b*NR*NN + r*NN + l,    e0*rinv);   // role_prob
    wout(2560 + (size_t)b*NR*NN + r*NN + l+32, e1*rinv);
  }
  if (tid == 224){   // idle lane in the softmax phase
    float m = -1e30f;
    for (int a=0;a<NA;a++) m = fmaxf(m, sOm[a]);
    float e[NA]; float ssum = 0.f;
    for (int a=0;a<NA;a++){ e[a] = __expf(sOm[a]-m); ssum += e[a]; }
    for (int a=0;a<NA;a++) wout(b*NA + a, e[a]/ssum);  // instr_prob
  }
}

extern "C" void kernel_launch(void* const* d_in, const int* in_sizes, int n_in,
                              void* d_out, int out_size, void* d_ws, size_t ws_size,
                              hipStream_t stream)
{
  const int* adj = (const int*)d_in[3];
  float* ws = (float*)d_ws;

  conv_in<<<(CONV_TOTAL+255)/256, 256, 0, stream>>>(
      d_in[0], d_in[1], d_in[2],
      d_in[4], d_in[5], d_in[6], d_in[7],
      d_in[8], d_in[9], d_in[10], d_in[11],
      d_in[12], d_in[13], d_in[14], d_in[15],
      d_in[16], d_in[17], d_in[18], d_in[19],
      d_in[20], d_in[21], ws);

  dir_kernel<<<1024, 256, 0, stream>>>(adj, ws);

  head_kernel<<<512, 256, 0, stream>>>(ws, d_out);
}

// Round 9
// 252.380 us; speedup vs baseline: 1.1547x; 1.0179x over previous
//
#include <hip/hip_runtime.h>
#include <hip/hip_bf16.h>

#define NN 64
#define BATCH 512
#define SP 60
#define SG 180
#define SEX 10
#define CATD 80
#define NA 5
#define NR 7
#define OO 8
#define II 8

typedef unsigned long long u64;
typedef unsigned short u16;
typedef unsigned int u32;
typedef unsigned char u8;

// ---- workspace layout (float offsets) ----
#define OFF_Z     0
#define OFF_DZ    327680
#define OFF_HAS   655360
#define OFF_WIHF  688128
#define OFF_WHHF  698928
#define OFF_BIHF  709728
#define OFF_BHHF  709908
#define OFF_WIHB  710088
#define OFF_WHHB  720888
#define OFF_BIHB  731688
#define OFF_BHHB  731868
#define OFF_WF    732048
#define OFF_BF    736848
#define OFF_WB    736908
#define OFF_BB    741708
#define OFF_WA    741768
#define OFF_BA    742368
#define OFF_WC    742373
#define OFF_BC    742493
#define OFF_WU    742494
#define OFF_BU    743334
#define CONV_TOTAL 743341
#define OFF_FLAG  743342
#define OFF_RHOF  743344
#define OFF_RHOB  (OFF_RHOF + 1966080)
#define OFF_ALF   (OFF_RHOB + 1966080)
#define OFF_ALB   (OFF_ALF + 30720)
#define OUT_TOTAL 232448

typedef _Float16 f16;
typedef _Float16 half2_t __attribute__((ext_vector_type(2)));
typedef _Float16 f16x8 __attribute__((ext_vector_type(8)));
typedef float f32x4 __attribute__((ext_vector_type(4)));

__device__ __forceinline__ float us2f(u16 v){
  return __uint_as_float(((u32)v) << 16);
}
__device__ __forceinline__ u16 f2bf(float f){
  __hip_bfloat16 h = __float2bfloat16(f);
  return *reinterpret_cast<u16*>(&h);
}
__device__ __forceinline__ float rcp_(float x){ return __builtin_amdgcn_rcpf(x); }
__device__ __forceinline__ float sigm(float x){
  return rcp_(1.f + __expf(-x));
}
__device__ __forceinline__ float tanh_(float x){
  float e = __expf(2.f*fabsf(x));
  float t = 1.f - 2.f*rcp_(e + 1.f);
  return copysignf(t, x);
}
__device__ __forceinline__ u32 pack2(float a, float b){
  half2_t h; h[0] = (f16)a; h[1] = (f16)b;
  return __builtin_bit_cast(u32, h);
}
__device__ __forceinline__ float fdot2_(u32 a, u32 b, float c){
  return __builtin_amdgcn_fdot2(__builtin_bit_cast(half2_t, a),
                                __builtin_bit_cast(half2_t, b), c, false);
}
__device__ __forceinline__ f16x8 bc16(uint4 v){ return __builtin_bit_cast(f16x8, v); }
__device__ __forceinline__ f32x4 mfma16(f16x8 a, f16x8 b, f32x4 c){
  return __builtin_amdgcn_mfma_f32_16x16x32_f16(a, b, c, 0, 0, 0);
}

// has is exactly {0,1}. f32 words: only 0x00000000 / 0x3F800000.
// bf16-pair words: 0x3F803F80 == (1.0,1.0) appears w.p. ~0.81 per pair.
// r18: cooperative detect — wave 0 scans the 1KB (4 words/lane) + ballot.
__global__ __launch_bounds__(256) void conv_in(
  const void* z, const void* dz, const void* has,
  const void* WihF, const void* WhhF, const void* bihF, const void* bhhF,
  const void* WihB, const void* WhhB, const void* bihB, const void* bhhB,
  const void* Wf_, const void* bf_, const void* Wb_, const void* bb_,
  const void* Wa, const void* ba, const void* Wc, const void* bc,
  const void* Wu, const void* bu, float* ws)
{
  __shared__ int sIsBf;
  const int tid = threadIdx.x;
  if (tid < 64){
    const u32* w = (const u32*)has;
    int f = 0;
    #pragma unroll
    for (int k=0;k<4;k++) f |= (w[tid*4 + k] == 0x3F803F80u) ? 1 : 0;
    u64 m = __ballot(f != 0);
    if (tid == 0) sIsBf = (m != 0ULL) ? 1 : 0;
  }
  __syncthreads();
  const int isbf = sIsBf;
  if (blockIdx.x == 0 && tid == 0) ws[OFF_FLAG] = (float)isbf;
  int idx = blockIdx.x*256 + tid;
  if (idx >= CONV_TOTAL) return;
  const void* src; int loc;
  if      (idx < OFF_DZ  ){ src=z;    loc=idx-OFF_Z;    }
  else if (idx < OFF_HAS ){ src=dz;   loc=idx-OFF_DZ;   }
  else if (idx < OFF_WIHF){ src=has;  loc=idx-OFF_HAS;  }
  else if (idx < OFF_WHHF){ src=WihF; loc=idx-OFF_WIHF; }
  else if (idx < OFF_BIHF){ src=WhhF; loc=idx-OFF_WHHF; }
  else if (idx < OFF_BHHF){ src=bihF; loc=idx-OFF_BIHF; }
  else if (idx < OFF_WIHB){ src=bhhF; loc=idx-OFF_BHHF; }
  else if (idx < OFF_WHHB){ src=WihB; loc=idx-OFF_WIHB; }
  else if (idx < OFF_BIHB){ src=WhhB; loc=idx-OFF_WHHB; }
  else if (idx < OFF_BHHB){ src=bihB; loc=idx-OFF_BIHB; }
  else if (idx < OFF_WF  ){ src=bhhB; loc=idx-OFF_BHHB; }
  else if (idx < OFF_BF  ){ src=Wf_;  loc=idx-OFF_WF;   }
  else if (idx < OFF_WB  ){ src=bf_;  loc=idx-OFF_BF;   }
  else if (idx < OFF_BB  ){ src=Wb_;  loc=idx-OFF_WB;   }
  else if (idx < OFF_WA  ){ src=bb_;  loc=idx-OFF_BB;   }
  else if (idx < OFF_BA  ){ src=Wa;   loc=idx-OFF_WA;   }
  else if (idx < OFF_WC  ){ src=ba;   loc=idx-OFF_BA;   }
  else if (idx < OFF_BC  ){ src=Wc;   loc=idx-OFF_WC;   }
  else if (idx < OFF_WU  ){ src=bc;   loc=idx-OFF_BC;   }
  else if (idx < OFF_BU  ){ src=Wu;   loc=idx-OFF_WU;   }
  else                    { src=bu;   loc=idx-OFF_BU;   }
  float v = isbf ? us2f(((const u16*)src)[loc]) : ((const float*)src)[loc];
  ws[idx] = v;
}

// r19 (resubmitted; R8 was an infra failure, never measured):
// 2 batch elements per block (TLP -> ILP trade).
// Weights/adj/consumer lists are batch-independent -> shared; h-state,
// rho-pad/hist, zdc, z/dz double (LDS ~62KB, 2 blocks/CU, 2 waves/SIMD).
// Each wave carries two independent dependency chains per step -> the
// matvec/gate MFMA+trans latencies of elem0 and elem1 hide each other,
// and the 2 barriers/step serve both elements. Grid 512 blocks.
// Inactive element (has=0) runs the same code with bl=0: gates write hold
// back bit-identically (f16->f32->f16 exact), so both elems execute in one
// straight-line region for max scheduling freedom.
__global__ __launch_bounds__(256, 2) void dir_kernel(const int* __restrict__ adj,
                                                     float* __restrict__ ws)
{
  const int tid = threadIdx.x;
  const int w   = tid >> 6;         // wave id (0..3) == row tile mt
  const int u   = tid & 63;         // lane
  const int ml  = u & 15;           // MFMA col (consumer slot)
  const int q   = u >> 4;           // MFMA quad
  const int bid = blockIdx.x;
  const int bwd = bid >> 8;
  const int bp  = (bid & 255) << 1; // batch pair base {bp, bp+1}

  const float* Wih  = ws + (bwd ? OFF_WIHB : OFF_WIHF);
  const float* Whh  = ws + (bwd ? OFF_WHHB : OFF_WHHF);
  const float* bih  = ws + (bwd ? OFF_BIHB : OFF_BIHF);
  const float* bhh  = ws + (bwd ? OFF_BHHB : OFF_BHHF);
  const float* Wcat = ws + (bwd ? OFF_WB   : OFF_WF);
  const float* bcat = ws + (bwd ? OFF_BB   : OFF_BF);
  const float* zc   = ws + OFF_Z;
  const float* dzc  = ws + OFF_DZ;
  const float* hasc = ws + OFF_HAS;
  float* rho   = ws + (bwd ? OFF_RHOB : OFF_RHOF);  // [64][512][60]
  float* alpha = ws + (bwd ? OFF_ALB  : OFF_ALF);   // [512][60]

  __shared__ uint4 sH4[2][65][9];     // h rows per elem; half63=1.0 (bias ch)
  __shared__ uint4 sRhoPad[2][8];     // rho_t halves; half63=1.0
  __shared__ uint4 sRhoHist[2][8][8]; // tail rho history; half63=1.0
  __shared__ float sZdc[2][NN][SP];   // precomputed bias + z/dz contribution
  __shared__ u32 sZp[2][NN][5];
  __shared__ u32 sDZp[2][NN][5];
  __shared__ float sHas[2][NN];
  __shared__ u64 sRowM[NN];
  __shared__ u8 sConsL[NN][64];       // consumer lists (batch-independent)
  __shared__ int sConsCnt[NN];

  #define ROWB(E,I) ((char*)&sH4[(E)][(I)][0])
  const u32 BIASW = 0x3C000000u;      // halves {0, 1.0h}

  // ---- staging ----
  {
    if (tid < 64){
      u64 rowm = 0;
      for (int j=0;j<64;j++) rowm |= ((u64)(adj[tid*64+j]!=0))<<j;
      sRowM[tid] = rowm;
    }
    if (tid < 128){
      const int e = tid >> 6, n = tid & 63;
      sHas[e][n] = hasc[(bp+e)*NN + n];
    }
    for (int idx=tid; idx<2*65*9; idx+=256){
      uint4 v = {0,0,0,0};
      if ((idx % 9) == 7) v.w = BIASW;       // half63 = 1.0
      ((uint4*)sH4)[idx] = v;
    }
    if (tid < 16){ uint4 v={0,0,0,0}; if ((tid&7)==7) v.w = BIASW; ((uint4*)sRhoPad)[tid]=v; }
    if (tid < 128){ uint4 v={0,0,0,0}; if ((tid&7)==7) v.w = BIASW; ((uint4*)sRhoHist)[tid]=v; }
    for (int idx=tid; idx<2*NN*5; idx+=256){
      int e = idx/(NN*5), rem = idx%(NN*5), n2=rem/5, p2=rem%5;
      sZp [e][n2][p2] = pack2(zc [(size_t)(bp+e)*NN*SEX + n2*SEX + 2*p2],
                              zc [(size_t)(bp+e)*NN*SEX + n2*SEX + 2*p2+1]);
      sDZp[e][n2][p2] = pack2(dzc[(size_t)(bp+e)*NN*SEX + n2*SEX + 2*p2],
                              dzc[(size_t)(bp+e)*NN*SEX + n2*SEX + 2*p2+1]);
    }
  }
  __syncthreads();
  if (tid < 64){
    u64 cm = 0;
    if (bwd) for (int i2=0;i2<64;i2++) cm |= ((sRowM[i2]>>tid)&1ULL)<<i2;
    u64 m = bwd ? cm : sRowM[tid];          // consumers of node tid
    int c = 0;
    while (m){ int i2 = (int)__builtin_ctzll(m); m &= m-1; sConsL[tid][c++] = (u8)i2; }
    sConsCnt[tid] = c;
  }
  // zdc precompute: sZdc[e][t][uu] = bcat[uu] + Wz.z + Wdz.dz (bias folded).
  // Wave tw handles (e,t) pairs et = tw, tw+4, ... (32 each).
  {
    const int uu = tid & 63;
    const int tw = tid >> 6;
    if (uu < SP){
      u32 wz[10];
      #pragma unroll
      for (int p=0;p<10;p++)
        wz[p] = pack2(Wcat[uu*CATD + 60 + 2*p], Wcat[uu*CATD + 60 + 2*p + 1]);
      const float bb0 = bcat[uu];
      for (int et=tw; et<2*NN; et+=4){
        const int e = et >> 6, t2 = et & 63;
        float c = bb0;
        #pragma unroll
        for (int p=0;p<5;p++){
          c = fdot2_(wz[p],   sZp [e][t2][p], c);
          c = fdot2_(wz[5+p], sDZp[e][t2][p], c);
        }
        sZdc[e][t2][uu] = c;
      }
    }
  }

  // ---- A fragments (wave w owns mt = w): lane (q,ml) holds
  // A[row=16w+ml][K=32kt+8q+j] ---- (shared across both batch elements)
  f16x8 Ar[4], Az[4], Anh[2], Ani[2], Ac[2];
  {
    const int R = 16*w + ml;
    const bool rok = (R < SP);
    #pragma unroll
    for (int kt=0; kt<4; kt++){
      f16x8 vr, vz;
      #pragma unroll
      for (int j=0;j<8;j++){
        const int K = 32*kt + 8*q + j;
        float wr=0.f, wz2=0.f;
        if (rok){
          if (K < SP){ wr = Whh[R*SP+K]; wz2 = Whh[(60+R)*SP+K]; }
          else if (K >= 64 && K < 64+SP){ wr = Wih[R*SP+(K-64)]; wz2 = Wih[(60+R)*SP+(K-64)]; }
          else if (K == 127){ wr = bhh[R]+bih[R]; wz2 = bhh[60+R]+bih[60+R]; }
        }
        vr[j]=(f16)wr; vz[j]=(f16)wz2;
      }
      Ar[kt]=vr; Az[kt]=vz;
    }
    #pragma unroll
    for (int kt=0; kt<2; kt++){
      f16x8 vn, vi, vc;
      #pragma unroll
      for (int j=0;j<8;j++){
        const int K = 32*kt + 8*q + j;
        float wn=0.f, wi=0.f, wcv=0.f;
        if (rok){
          if (K < SP){ wn = Whh[(120+R)*SP+K]; wi = Wih[(120+R)*SP+K]; wcv = Wcat[R*CATD+K]; }
          else if (K == 63){ wn = bhh[120+R]; wi = bih[120+R]; }
        }
        vn[j]=(f16)wn; vi[j]=(f16)wi; vc[j]=(f16)wcv;
      }
      Anh[kt]=vn; Ani[kt]=vi; Ac[kt]=vc;
    }
  }
  __syncthreads();   // lists + zdc + LDS init visible

  // gates: GRU gate math + h read-modify-write, window [32w,32w+32) of rowb.
  auto gates = [&](f32x4 Dr, f32x4 Dz, f32x4 Dn, f32x4 Gn,
                   char* rowb, bool wr, float bl){
    char* rp = rowb + 32*w + 8*q;
    uint2 h2 = *(uint2*)rp;
    half2_t ha = __builtin_bit_cast(half2_t, h2.x);
    half2_t hb = __builtin_bit_cast(half2_t, h2.y);
    float hold[4] = { (float)ha[0], (float)ha[1], (float)hb[0], (float)hb[1] };
    float hw[4];
    #pragma unroll
    for (int reg=0;reg<4;reg++){
      float r_ = sigm(Dr[reg]);
      float zg = sigm(Dz[reg]);
      float nv = tanh_(Gn[reg] + r_*Dn[reg]);
      float hn_ = (1.f - zg)*nv + zg*hold[reg];
      hw[reg] = (bl != 0.f) ? hn_ : hold[reg];   // bl is exactly 0 or 1
    }
    if (wr && !(w==3 && q==3)){
      uint2 o; o.x = pack2(hw[0],hw[1]); o.y = pack2(hw[2],hw[3]);
      *(uint2*)rp = o;
    }
  };

  // full 11-MFMA pass (groups p>=2 [absent for this input] + tail)
  auto fullpass = [&](f16x8 Bh0, f16x8 Bh1, f16x8 Br0, f16x8 Br1,
                      f32x4 Gn, char* rowb, bool wr, float bl){
    f32x4 Dr={0,0,0,0}, Dz={0,0,0,0}, Dn={0,0,0,0};
    Dr = mfma16(Ar[0], Bh0, Dr); Dr = mfma16(Ar[1], Bh1, Dr);
    Dr = mfma16(Ar[2], Br0, Dr); Dr = mfma16(Ar[3], Br1, Dr);
    Dz = mfma16(Az[0], Bh0, Dz); Dz = mfma16(Az[1], Bh1, Dz);
    Dz = mfma16(Az[2], Br0, Dz); Dz = mfma16(Az[3], Br1, Dz);
    Dn = mfma16(Anh[0], Bh0, Dn); Dn = mfma16(Anh[1], Bh1, Dn);
    gates(Dr, Dz, Dn, Gn, rowb, wr, bl);
  };

  // ---- 64 pipelined steps, 2 barriers each, 2 batch elems ----
  int t = bwd ? 63 : 0;
  const int dt = bwd ? -1 : 1;
  for (int s=0; s<64; s++, t+=dt){
    const int cnt = sConsCnt[t];
    const float bl0 = sHas[0][t];
    const float bl1 = sHas[1][t];
    const bool act = (cnt > 0) && (bl0 != 0.f || bl1 != 0.f);
    const bool g1  = act && (cnt > 16);

    // pre-R: consumer-row Bh preloads, both elems (reads only)
    int ci0 = 64, ci1 = 64;
    f16x8 Bh0e0={}, Bh1e0={}, Bh0e1={}, Bh1e1={};
    f16x8 Ch0e0={}, Ch1e0={}, Ch0e1={}, Ch1e1={};
    if (act){
      ci0 = (ml < cnt) ? (int)sConsL[t][ml] : 64;
      Bh0e0 = bc16(sH4[0][ci0][q]); Bh1e0 = bc16(sH4[0][ci0][4+q]);
      Bh0e1 = bc16(sH4[1][ci0][q]); Bh1e1 = bc16(sH4[1][ci0][4+q]);
      if (g1){
        ci1 = (16 + ml < cnt) ? (int)sConsL[t][16 + ml] : 64;
        Ch0e0 = bc16(sH4[0][ci1][q]); Ch1e0 = bc16(sH4[0][ci1][4+q]);
        Ch0e1 = bc16(sH4[1][ci1][q]); Ch1e1 = bc16(sH4[1][ci1][4+q]);
      }
    }

    // phase 1 matvec x2: rho_raw = Wch @ h_t via broadcast-B MFMA.
    {
      const f16x8 H00 = bc16(sH4[0][t][q]);
      const f16x8 H01 = bc16(sH4[0][t][4+q]);
      const f16x8 H10 = bc16(sH4[1][t][q]);
      const f16x8 H11 = bc16(sH4[1][t][4+q]);
      f32x4 Rv0 = {0,0,0,0}, Rv1 = {0,0,0,0};
      Rv0 = mfma16(Ac[0], H00, Rv0);
      Rv1 = mfma16(Ac[0], H10, Rv1);
      Rv0 = mfma16(Ac[1], H01, Rv0);
      Rv1 = mfma16(Ac[1], H11, Rv1);
      const int row = 16*w + 4*q + ml;     // valid for ml<4
      if (ml < 4 && row < SP){
        float v0 = Rv0[0], v1 = Rv1[0];
        v0 = (ml==1) ? Rv0[1] : v0;  v1 = (ml==1) ? Rv1[1] : v1;
        v0 = (ml==2) ? Rv0[2] : v0;  v1 = (ml==2) ? Rv1[2] : v1;
        v0 = (ml==3) ? Rv0[3] : v0;  v1 = (ml==3) ? Rv1[3] : v1;
        v0 += sZdc[0][t][row];
        v1 += sZdc[1][t][row];
        if (!bwd){ v0 = tanh_(v0); v1 = tanh_(v1); }
        *(f16*)((char*)&sRhoPad[0][0] + 2*row) = (f16)v0;
        *(f16*)((char*)&sRhoPad[1][0] + 2*row) = (f16)v1;
        const int slot = bwd ? t : (t - (NN-OO));
        if (slot >= 0 && slot < 8){
          *(f16*)((char*)&sRhoHist[0][slot][0] + 2*row) = (f16)v0;
          *(f16*)((char*)&sRhoHist[1][slot][0] + 2*row) = (f16)v1;
        }
        rho[((size_t)t*BATCH + bp  )*SP + row] = v0;   // fire & forget
        rho[((size_t)t*BATCH + bp+1)*SP + row] = v1;
      }
    }
    __syncthreads();   // R: rho visible; pre-R h reads done before writes

    if (act){
      const f16x8 Br0e0 = bc16(sRhoPad[0][q]);
      const f16x8 Br1e0 = bc16(sRhoPad[0][4+q]);
      const f16x8 Br0e1 = bc16(sRhoPad[1][q]);
      const f16x8 Br1e1 = bc16(sRhoPad[1][4+q]);
      // consumer-independent accumulators, interleaved elem0/elem1
      f32x4 Gn0={0,0,0,0}, Gn1={0,0,0,0};
      Gn0 = mfma16(Ani[0], Br0e0, Gn0);  Gn1 = mfma16(Ani[0], Br0e1, Gn1);
      Gn0 = mfma16(Ani[1], Br1e0, Gn0);  Gn1 = mfma16(Ani[1], Br1e1, Gn1);
      f32x4 Pr0={0,0,0,0}, Pr1={0,0,0,0};
      Pr0 = mfma16(Ar[2], Br0e0, Pr0);   Pr1 = mfma16(Ar[2], Br0e1, Pr1);
      Pr0 = mfma16(Ar[3], Br1e0, Pr0);   Pr1 = mfma16(Ar[3], Br1e1, Pr1);
      f32x4 Pz0={0,0,0,0}, Pz1={0,0,0,0};
      Pz0 = mfma16(Az[2], Br0e0, Pz0);   Pz1 = mfma16(Az[2], Br0e1, Pz1);
      Pz0 = mfma16(Az[3], Br1e0, Pz0);   Pz1 = mfma16(Az[3], Br1e1, Pz1);

      { // group 0, both elems interleaved
        f32x4 Dr0=Pr0, Dz0=Pz0, Dn0={0,0,0,0};
        f32x4 Dr1=Pr1, Dz1=Pz1, Dn1={0,0,0,0};
        Dr0 = mfma16(Ar[0], Bh0e0, Dr0);  Dr1 = mfma16(Ar[0], Bh0e1, Dr1);
        Dr0 = mfma16(Ar[1], Bh1e0, Dr0);  Dr1 = mfma16(Ar[1], Bh1e1, Dr1);
        Dz0 = mfma16(Az[0], Bh0e0, Dz0);  Dz1 = mfma16(Az[0], Bh0e1, Dz1);
        Dz0 = mfma16(Az[1], Bh1e0, Dz0);  Dz1 = mfma16(Az[1], Bh1e1, Dz1);
        Dn0 = mfma16(Anh[0], Bh0e0, Dn0); Dn1 = mfma16(Anh[0], Bh0e1, Dn1);
        Dn0 = mfma16(Anh[1], Bh1e0, Dn0); Dn1 = mfma16(Anh[1], Bh1e1, Dn1);
        gates(Dr0, Dz0, Dn0, Gn0, ROWB(0,ci0), ml < cnt, bl0);
        gates(Dr1, Dz1, Dn1, Gn1, ROWB(1,ci0), ml < cnt, bl1);
      }
      if (g1){
        f32x4 Dr0=Pr0, Dz0=Pz0, Dn0={0,0,0,0};
        f32x4 Dr1=Pr1, Dz1=Pz1, Dn1={0,0,0,0};
        Dr0 = mfma16(Ar[0], Ch0e0, Dr0);  Dr1 = mfma16(Ar[0], Ch0e1, Dr1);
        Dr0 = mfma16(Ar[1], Ch1e0, Dr0);  Dr1 = mfma16(Ar[1], Ch1e1, Dr1);
        Dz0 = mfma16(Az[0], Ch0e0, Dz0);  Dz1 = mfma16(Az[0], Ch0e1, Dz1);
        Dz0 = mfma16(Az[1], Ch1e0, Dz0);  Dz1 = mfma16(Az[1], Ch1e1, Dz1);
        Dn0 = mfma16(Anh[0], Ch0e0, Dn0); Dn1 = mfma16(Anh[0], Ch0e1, Dn1);
        Dn0 = mfma16(Anh[1], Ch1e0, Dn0); Dn1 = mfma16(Anh[1], Ch1e1, Dn1);
        gates(Dr0, Dz0, Dn0, Gn0, ROWB(0,ci1), 16 + ml < cnt, bl0);
        gates(Dr1, Dz1, Dn1, Gn1, ROWB(1,ci1), 16 + ml < cnt, bl1);
      }
      // groups p>=2 (absent for this input, kept for generality)
      for (int p=2; 16*p < cnt; p++){
        const int idxp = 16*p + ml;
        const int ci = (idxp < cnt) ? (int)sConsL[t][idxp] : 64;
        fullpass(bc16(sH4[0][ci][q]), bc16(sH4[0][ci][4+q]),
                 Br0e0, Br1e0, Gn0, ROWB(0,ci), idxp < cnt, bl0);
        fullpass(bc16(sH4[1][ci][q]), bc16(sH4[1][ci][4+q]),
                 Br0e1, Br1e1, Gn1, ROWB(1,ci), idxp < cnt, bl1);
      }
    }
    __syncthreads();   // C: h writes visible to next step's reads
  }

  // ---- alpha tail: 8 GRU steps on scratch row 64, both elems ----
  for (int s2=0; s2<8; s2++){
    const int i = bwd ? (7 - s2) : (NN - OO + s2);
    const int slot = bwd ? i : (i - (NN-OO));
    const f16x8 Th00 = bc16(sH4[0][64][q]);
    const f16x8 Th01 = bc16(sH4[0][64][4+q]);
    const f16x8 Th10 = bc16(sH4[1][64][q]);
    const f16x8 Th11 = bc16(sH4[1][64][4+q]);
    const f16x8 Tr00 = bc16(sRhoHist[0][slot][q]);
    const f16x8 Tr01 = bc16(sRhoHist[0][slot][4+q]);
    const f16x8 Tr10 = bc16(sRhoHist[1][slot][q]);
    const f16x8 Tr11 = bc16(sRhoHist[1][slot][4+q]);
    f32x4 Gt0={0,0,0,0}, Gt1={0,0,0,0};
    Gt0 = mfma16(Ani[0], Tr00, Gt0);  Gt1 = mfma16(Ani[0], Tr10, Gt1);
    Gt0 = mfma16(Ani[1], Tr01, Gt0);  Gt1 = mfma16(Ani[1], Tr11, Gt1);
    __syncthreads();   // all waves' row-64 reads done before writes
    fullpass(Th00, Th01, Tr00, Tr01, Gt0, ROWB(0,64), ml==0, sHas[0][i]);
    fullpass(Th10, Th11, Tr10, Tr11, Gt1, ROWB(1,64), ml==0, sHas[1][i]);
    __syncthreads();   // writes visible to next tail step
  }
  if (tid < SP){
    alpha[(size_t)(bp  )*SP + tid] = (float)*(const f16*)(ROWB(0,64) + 2*tid);
    alpha[(size_t)(bp+1)*SP + tid] = (float)*(const f16*)(ROWB(1,64) + 2*tid);
  }
  #undef ROWB
}

// One block per batch element: psi + softmaxes, omega, value -> d_out directly.
// r18: float2 LDS reads for psi; softmax 7x32 lanes with shfl_xor.
__global__ __launch_bounds__(256, 1) void head_kernel(float* __restrict__ ws,
                                                      void* __restrict__ outp)
{
  const int b = blockIdx.x;
  const int tid = threadIdx.x;
  const int isbf = (ws[OFF_FLAG] != 0.f);
  const float* hasc   = ws + OFF_HAS;
  const float* WaC    = ws + OFF_WA;
  const float* baC    = ws + OFF_BA;
  const float* WcC    = ws + OFF_WC;
  const float* bcC    = ws + OFF_BC;
  const float* WuC    = ws + OFF_WU;
  const float* buC    = ws + OFF_BU;
  const float* rhoF   = ws + OFF_RHOF;
  const float* rhoB   = ws + OFF_RHOB;
  const float* alphaF = ws + OFF_ALF;
  const float* alphaB = ws + OFF_ALB;

  __shared__ float sF[NN][122];    // 488B stride: float2-aligned
  __shared__ float sAB[120];
  __shared__ float sWu[NR*120];
  __shared__ float sHasR[NN];
  __shared__ float sPsi[NR][NN];
  __shared__ float sOm[NA];

  auto wout = [&](int idx, float v){
    if (isbf) ((u16*)outp)[idx] = f2bf(v);
    else      ((float*)outp)[idx] = v;
  };

  for (int idx=tid; idx<NN*SP; idx+=256){
    int n = idx/SP, s = idx%SP;
    sF[n][s]    = rhoF[((size_t)n*BATCH + b)*SP + s];
    sF[n][60+s] = rhoB[((size_t)n*BATCH + b)*SP + s];
  }
  for (int idx=tid; idx<120; idx+=256)
    sAB[idx] = (idx<60) ? alphaF[(size_t)b*SP + idx] : alphaB[(size_t)b*SP + idx-60];
  for (int idx=tid; idx<NR*120; idx+=256) sWu[idx] = WuC[idx];
  for (int idx=tid; idx<NN; idx+=256) sHasR[idx] = hasc[b*NN + idx];
  __syncthreads();

  for (int idx=tid; idx<NR*NN; idx+=256){
    int r = idx/NN, n = idx%NN;
    const float2* fn = (const float2*)&sF[n][0];
    const float2* wr = (const float2*)&sWu[r*120];
    float acc = buC[r];
    #pragma unroll 6
    for (int s2=0;s2<60;s2++){
      float2 a = fn[s2], c = wr[s2];
      acc += a.x*c.x;
      acc += a.y*c.y;
    }
    sPsi[r][n] = (sHasR[n] != 0.f) ? acc : -60.f;
  }
  if (tid >= 64 && tid < 64+NA){
    int a = tid - 64;
    float acc = baC[a];
    for (int s=0;s<120;s++) acc += sAB[s]*WaC[a*120+s];
    sOm[a] = acc;
  }
  if (tid == 70){
    float acc = bcC[0];
    for (int s=0;s<120;s++) acc += sAB[s]*WcC[s];
    wout(2560 + BATCH*NR*NN + b, acc);                 // value
  }
  __syncthreads();

  if (tid < NR*32){
    const int r = tid >> 5, l = tid & 31;
    float v0 = sPsi[r][l], v1 = sPsi[r][l+32];
    float m = fmaxf(v0, v1);
    #pragma unroll
    for (int o=16;o>0;o>>=1) m = fmaxf(m, __shfl_xor(m, o, 64));
    float e0 = __expf(v0 - m), e1 = __expf(v1 - m);
    float ssum = e0 + e1;
    #pragma unroll
    for (int o=16;o>0;o>>=1) ssum += __shfl_xor(ssum, o, 64);
    float rinv = 1.f/ssum;
    wout(2560 + (size_t)b*NR*NN + r*NN + l,    e0*rinv);   // role_prob
    wout(2560 + (size_t)b*NR*NN + r*NN + l+32, e1*rinv);
  }
  if (tid == 224){   // idle lane in the softmax phase
    float m = -1e30f;
    for (int a=0;a<NA;a++) m = fmaxf(m, sOm[a]);
    float e[NA]; float ssum = 0.f;
    for (int a=0;a<NA;a++){ e[a] = __expf(sOm[a]-m); ssum += e[a]; }
    for (int a=0;a<NA;a++) wout(b*NA + a, e[a]/ssum);  // instr_prob
  }
}

extern "C" void kernel_launch(void* const* d_in, const int* in_sizes, int n_in,
                              void* d_out, int out_size, void* d_ws, size_t ws_size,
                              hipStream_t stream)
{
  const int* adj = (const int*)d_in[3];
  float* ws = (float*)d_ws;

  conv_in<<<(CONV_TOTAL+255)/256, 256, 0, stream>>>(
      d_in[0], d_in[1], d_in[2],
      d_in[4], d_in[5], d_in[6], d_in[7],
      d_in[8], d_in[9], d_in[10], d_in[11],
      d_in[12], d_in[13], d_in[14], d_in[15],
      d_in[16], d_in[17], d_in[18], d_in[19],
      d_in[20], d_in[21], ws);

  dir_kernel<<<512, 256, 0, stream>>>(adj, ws);

  head_kernel<<<512, 256, 0, stream>>>(ws, d_out);
}

// Round 10
// 246.762 us; speedup vs baseline: 1.1810x; 1.0228x over previous
//
#include <hip/hip_runtime.h>
#include <hip/hip_bf16.h>

#define NN 64
#define BATCH 512
#define SP 60
#define SG 180
#define SEX 10
#define CATD 80
#define NA 5
#define NR 7
#define OO 8
#define II 8

typedef unsigned long long u64;
typedef unsigned short u16;
typedef unsigned int u32;
typedef unsigned char u8;

// ---- workspace layout (float offsets) ----
#define OFF_Z     0
#define OFF_DZ    327680
#define OFF_HAS   655360
#define OFF_WIHF  688128
#define OFF_WHHF  698928
#define OFF_BIHF  709728
#define OFF_BHHF  709908
#define OFF_WIHB  710088
#define OFF_WHHB  720888
#define OFF_BIHB  731688
#define OFF_BHHB  731868
#define OFF_WF    732048
#define OFF_BF    736848
#define OFF_WB    736908
#define OFF_BB    741708
#define OFF_WA    741768
#define OFF_BA    742368
#define OFF_WC    742373
#define OFF_BC    742493
#define OFF_WU    742494
#define OFF_BU    743334
#define CONV_TOTAL 743341
#define OFF_FLAG  743342
#define OFF_RHOF  743344
#define OFF_RHOB  (OFF_RHOF + 1966080)
#define OFF_ALF   (OFF_RHOB + 1966080)
#define OFF_ALB   (OFF_ALF + 30720)
#define OUT_TOTAL 232448

typedef _Float16 f16;
typedef _Float16 half2_t __attribute__((ext_vector_type(2)));
typedef _Float16 f16x8 __attribute__((ext_vector_type(8)));
typedef float f32x4 __attribute__((ext_vector_type(4)));

__device__ __forceinline__ float us2f(u16 v){
  return __uint_as_float(((u32)v) << 16);
}
__device__ __forceinline__ u16 f2bf(float f){
  __hip_bfloat16 h = __float2bfloat16(f);
  return *reinterpret_cast<u16*>(&h);
}
__device__ __forceinline__ float rcp_(float x){ return __builtin_amdgcn_rcpf(x); }
__device__ __forceinline__ float sigm(float x){
  return rcp_(1.f + __expf(-x));
}
__device__ __forceinline__ float tanh_(float x){
  float e = __expf(2.f*fabsf(x));
  float t = 1.f - 2.f*rcp_(e + 1.f);
  return copysignf(t, x);
}
__device__ __forceinline__ u32 pack2(float a, float b){
  half2_t h; h[0] = (f16)a; h[1] = (f16)b;
  return __builtin_bit_cast(u32, h);
}
__device__ __forceinline__ float fdot2_(u32 a, u32 b, float c){
  return __builtin_amdgcn_fdot2(__builtin_bit_cast(half2_t, a),
                                __builtin_bit_cast(half2_t, b), c, false);
}
__device__ __forceinline__ f16x8 bc16(uint4 v){ return __builtin_bit_cast(f16x8, v); }
__device__ __forceinline__ f32x4 mfma16(f16x8 a, f16x8 b, f32x4 c){
  return __builtin_amdgcn_mfma_f32_16x16x32_f16(a, b, c, 0, 0, 0);
}

// has is exactly {0,1}. f32 words: only 0x00000000 / 0x3F800000.
// bf16-pair words: 0x3F803F80 == (1.0,1.0) appears w.p. ~0.81 per pair.
// r18: cooperative detect — wave 0 scans the 1KB (4 words/lane) + ballot.
__global__ __launch_bounds__(256) void conv_in(
  const void* z, const void* dz, const void* has,
  const void* WihF, const void* WhhF, const void* bihF, const void* bhhF,
  const void* WihB, const void* WhhB, const void* bihB, const void* bhhB,
  const void* Wf_, const void* bf_, const void* Wb_, const void* bb_,
  const void* Wa, const void* ba, const void* Wc, const void* bc,
  const void* Wu, const void* bu, float* ws)
{
  __shared__ int sIsBf;
  const int tid = threadIdx.x;
  if (tid < 64){
    const u32* w = (const u32*)has;
    int f = 0;
    #pragma unroll
    for (int k=0;k<4;k++) f |= (w[tid*4 + k] == 0x3F803F80u) ? 1 : 0;
    u64 m = __ballot(f != 0);
    if (tid == 0) sIsBf = (m != 0ULL) ? 1 : 0;
  }
  __syncthreads();
  const int isbf = sIsBf;
  if (blockIdx.x == 0 && tid == 0) ws[OFF_FLAG] = (float)isbf;
  int idx = blockIdx.x*256 + tid;
  if (idx >= CONV_TOTAL) return;
  const void* src; int loc;
  if      (idx < OFF_DZ  ){ src=z;    loc=idx-OFF_Z;    }
  else if (idx < OFF_HAS ){ src=dz;   loc=idx-OFF_DZ;   }
  else if (idx < OFF_WIHF){ src=has;  loc=idx-OFF_HAS;  }
  else if (idx < OFF_WHHF){ src=WihF; loc=idx-OFF_WIHF; }
  else if (idx < OFF_BIHF){ src=WhhF; loc=idx-OFF_WHHF; }
  else if (idx < OFF_BHHF){ src=bihF; loc=idx-OFF_BIHF; }
  else if (idx < OFF_WIHB){ src=bhhF; loc=idx-OFF_BHHF; }
  else if (idx < OFF_WHHB){ src=WihB; loc=idx-OFF_WIHB; }
  else if (idx < OFF_BIHB){ src=WhhB; loc=idx-OFF_WHHB; }
  else if (idx < OFF_BHHB){ src=bihB; loc=idx-OFF_BIHB; }
  else if (idx < OFF_WF  ){ src=bhhB; loc=idx-OFF_BHHB; }
  else if (idx < OFF_BF  ){ src=Wf_;  loc=idx-OFF_WF;   }
  else if (idx < OFF_WB  ){ src=bf_;  loc=idx-OFF_BF;   }
  else if (idx < OFF_BB  ){ src=Wb_;  loc=idx-OFF_WB;   }
  else if (idx < OFF_WA  ){ src=bb_;  loc=idx-OFF_BB;   }
  else if (idx < OFF_BA  ){ src=Wa;   loc=idx-OFF_WA;   }
  else if (idx < OFF_WC  ){ src=ba;   loc=idx-OFF_BA;   }
  else if (idx < OFF_BC  ){ src=Wc;   loc=idx-OFF_WC;   }
  else if (idx < OFF_WU  ){ src=bc;   loc=idx-OFF_BC;   }
  else if (idx < OFF_BU  ){ src=Wu;   loc=idx-OFF_WU;   }
  else                    { src=bu;   loc=idx-OFF_BU;   }
  float v = isbf ? us2f(((const u16*)src)[loc]) : ((const float*)src)[loc];
  ws[idx] = v;
}

// r20: r19 (2 elems/block, 150us) + mixed-column packing.
// MFMA's B operand is per-column (lane ml supplies col ml), so when
// cnt<=8 (~42% of steps) both elems' consumers fit one 16-col pass:
// cols 0-7 = elem0, 8-15 = elem1; per-lane e=ml>>3 selects rho-pad,
// blend, and target h-row. 12 MFMAs + 1 gates call replace 24 + 2.
// Matvec likewise packed every step: cols 0-3 elem0, 4-7 elem1 -> 2
// MFMAs instead of 4. Slow path (cnt>8) is r19's code verbatim.
__global__ __launch_bounds__(256, 2) void dir_kernel(const int* __restrict__ adj,
                                                     float* __restrict__ ws)
{
  const int tid = threadIdx.x;
  const int w   = tid >> 6;         // wave id (0..3) == row tile mt
  const int u   = tid & 63;         // lane
  const int ml  = u & 15;           // MFMA col (consumer slot)
  const int q   = u >> 4;           // MFMA quad
  const int bid = blockIdx.x;
  const int bwd = bid >> 8;
  const int bp  = (bid & 255) << 1; // batch pair base {bp, bp+1}

  const float* Wih  = ws + (bwd ? OFF_WIHB : OFF_WIHF);
  const float* Whh  = ws + (bwd ? OFF_WHHB : OFF_WHHF);
  const float* bih  = ws + (bwd ? OFF_BIHB : OFF_BIHF);
  const float* bhh  = ws + (bwd ? OFF_BHHB : OFF_BHHF);
  const float* Wcat = ws + (bwd ? OFF_WB   : OFF_WF);
  const float* bcat = ws + (bwd ? OFF_BB   : OFF_BF);
  const float* zc   = ws + OFF_Z;
  const float* dzc  = ws + OFF_DZ;
  const float* hasc = ws + OFF_HAS;
  float* rho   = ws + (bwd ? OFF_RHOB : OFF_RHOF);  // [64][512][60]
  float* alpha = ws + (bwd ? OFF_ALB  : OFF_ALF);   // [512][60]

  __shared__ uint4 sH4[2][65][9];     // h rows per elem; half63=1.0 (bias ch)
  __shared__ uint4 sRhoPad[2][8];     // rho_t halves; half63=1.0
  __shared__ uint4 sRhoHist[2][8][8]; // tail rho history; half63=1.0
  __shared__ float sZdc[2][NN][SP];   // precomputed bias + z/dz contribution
  __shared__ u32 sZp[2][NN][5];
  __shared__ u32 sDZp[2][NN][5];
  __shared__ float sHas[2][NN];
  __shared__ u64 sRowM[NN];
  __shared__ u8 sConsL[NN][64];       // consumer lists (batch-independent)
  __shared__ int sConsCnt[NN];

  #define ROWB(E,I) ((char*)&sH4[(E)][(I)][0])
  const u32 BIASW = 0x3C000000u;      // halves {0, 1.0h}

  // ---- staging ----
  {
    if (tid < 64){
      u64 rowm = 0;
      for (int j=0;j<64;j++) rowm |= ((u64)(adj[tid*64+j]!=0))<<j;
      sRowM[tid] = rowm;
    }
    if (tid < 128){
      const int e = tid >> 6, n = tid & 63;
      sHas[e][n] = hasc[(bp+e)*NN + n];
    }
    for (int idx=tid; idx<2*65*9; idx+=256){
      uint4 v = {0,0,0,0};
      if ((idx % 9) == 7) v.w = BIASW;       // half63 = 1.0
      ((uint4*)sH4)[idx] = v;
    }
    if (tid < 16){ uint4 v={0,0,0,0}; if ((tid&7)==7) v.w = BIASW; ((uint4*)sRhoPad)[tid]=v; }
    if (tid < 128){ uint4 v={0,0,0,0}; if ((tid&7)==7) v.w = BIASW; ((uint4*)sRhoHist)[tid]=v; }
    for (int idx=tid; idx<2*NN*5; idx+=256){
      int e = idx/(NN*5), rem = idx%(NN*5), n2=rem/5, p2=rem%5;
      sZp [e][n2][p2] = pack2(zc [(size_t)(bp+e)*NN*SEX + n2*SEX + 2*p2],
                              zc [(size_t)(bp+e)*NN*SEX + n2*SEX + 2*p2+1]);
      sDZp[e][n2][p2] = pack2(dzc[(size_t)(bp+e)*NN*SEX + n2*SEX + 2*p2],
                              dzc[(size_t)(bp+e)*NN*SEX + n2*SEX + 2*p2+1]);
    }
  }
  __syncthreads();
  if (tid < 64){
    u64 cm = 0;
    if (bwd) for (int i2=0;i2<64;i2++) cm |= ((sRowM[i2]>>tid)&1ULL)<<i2;
    u64 m = bwd ? cm : sRowM[tid];          // consumers of node tid
    int c = 0;
    while (m){ int i2 = (int)__builtin_ctzll(m); m &= m-1; sConsL[tid][c++] = (u8)i2; }
    sConsCnt[tid] = c;
  }
  // zdc precompute: sZdc[e][t][uu] = bcat[uu] + Wz.z + Wdz.dz (bias folded).
  // Wave tw handles (e,t) pairs et = tw, tw+4, ... (32 each).
  {
    const int uu = tid & 63;
    const int tw = tid >> 6;
    if (uu < SP){
      u32 wz[10];
      #pragma unroll
      for (int p=0;p<10;p++)
        wz[p] = pack2(Wcat[uu*CATD + 60 + 2*p], Wcat[uu*CATD + 60 + 2*p + 1]);
      const float bb0 = bcat[uu];
      for (int et=tw; et<2*NN; et+=4){
        const int e = et >> 6, t2 = et & 63;
        float c = bb0;
        #pragma unroll
        for (int p=0;p<5;p++){
          c = fdot2_(wz[p],   sZp [e][t2][p], c);
          c = fdot2_(wz[5+p], sDZp[e][t2][p], c);
        }
        sZdc[e][t2][uu] = c;
      }
    }
  }

  // ---- A fragments (wave w owns mt = w): lane (q,ml) holds
  // A[row=16w+ml][K=32kt+8q+j] ---- (shared across both batch elements)
  f16x8 Ar[4], Az[4], Anh[2], Ani[2], Ac[2];
  {
    const int R = 16*w + ml;
    const bool rok = (R < SP);
    #pragma unroll
    for (int kt=0; kt<4; kt++){
      f16x8 vr, vz;
      #pragma unroll
      for (int j=0;j<8;j++){
        const int K = 32*kt + 8*q + j;
        float wr=0.f, wz2=0.f;
        if (rok){
          if (K < SP){ wr = Whh[R*SP+K]; wz2 = Whh[(60+R)*SP+K]; }
          else if (K >= 64 && K < 64+SP){ wr = Wih[R*SP+(K-64)]; wz2 = Wih[(60+R)*SP+(K-64)]; }
          else if (K == 127){ wr = bhh[R]+bih[R]; wz2 = bhh[60+R]+bih[60+R]; }
        }
        vr[j]=(f16)wr; vz[j]=(f16)wz2;
      }
      Ar[kt]=vr; Az[kt]=vz;
    }
    #pragma unroll
    for (int kt=0; kt<2; kt++){
      f16x8 vn, vi, vc;
      #pragma unroll
      for (int j=0;j<8;j++){
        const int K = 32*kt + 8*q + j;
        float wn=0.f, wi=0.f, wcv=0.f;
        if (rok){
          if (K < SP){ wn = Whh[(120+R)*SP+K]; wi = Wih[(120+R)*SP+K]; wcv = Wcat[R*CATD+K]; }
          else if (K == 63){ wn = bhh[120+R]; wi = bih[120+R]; }
        }
        vn[j]=(f16)wn; vi[j]=(f16)wi; vc[j]=(f16)wcv;
      }
      Anh[kt]=vn; Ani[kt]=vi; Ac[kt]=vc;
    }
  }
  __syncthreads();   // lists + zdc + LDS init visible

  // gates: GRU gate math + h read-modify-write, window [32w,32w+32) of rowb.
  auto gates = [&](f32x4 Dr, f32x4 Dz, f32x4 Dn, f32x4 Gn,
                   char* rowb, bool wr, float bl){
    char* rp = rowb + 32*w + 8*q;
    uint2 h2 = *(uint2*)rp;
    half2_t ha = __builtin_bit_cast(half2_t, h2.x);
    half2_t hb = __builtin_bit_cast(half2_t, h2.y);
    float hold[4] = { (float)ha[0], (float)ha[1], (float)hb[0], (float)hb[1] };
    float hw[4];
    #pragma unroll
    for (int reg=0;reg<4;reg++){
      float r_ = sigm(Dr[reg]);
      float zg = sigm(Dz[reg]);
      float nv = tanh_(Gn[reg] + r_*Dn[reg]);
      float hn_ = (1.f - zg)*nv + zg*hold[reg];
      hw[reg] = (bl != 0.f) ? hn_ : hold[reg];   // bl is exactly 0 or 1
    }
    if (wr && !(w==3 && q==3)){
      uint2 o; o.x = pack2(hw[0],hw[1]); o.y = pack2(hw[2],hw[3]);
      *(uint2*)rp = o;
    }
  };

  // full 11-MFMA pass (groups p>=2 [absent for this input] + tail)
  auto fullpass = [&](f16x8 Bh0, f16x8 Bh1, f16x8 Br0, f16x8 Br1,
                      f32x4 Gn, char* rowb, bool wr, float bl){
    f32x4 Dr={0,0,0,0}, Dz={0,0,0,0}, Dn={0,0,0,0};
    Dr = mfma16(Ar[0], Bh0, Dr); Dr = mfma16(Ar[1], Bh1, Dr);
    Dr = mfma16(Ar[2], Br0, Dr); Dr = mfma16(Ar[3], Br1, Dr);
    Dz = mfma16(Az[0], Bh0, Dz); Dz = mfma16(Az[1], Bh1, Dz);
    Dz = mfma16(Az[2], Br0, Dz); Dz = mfma16(Az[3], Br1, Dz);
    Dn = mfma16(Anh[0], Bh0, Dn); Dn = mfma16(Anh[1], Bh1, Dn);
    gates(Dr, Dz, Dn, Gn, rowb, wr, bl);
  };

  // ---- 64 pipelined steps, 2 barriers each, 2 batch elems ----
  int t = bwd ? 63 : 0;
  const int dt = bwd ? -1 : 1;
  for (int s=0; s<64; s++, t+=dt){
    const int cnt = sConsCnt[t];
    const float bl0 = sHas[0][t];
    const float bl1 = sHas[1][t];
    const bool act   = (cnt > 0) && (bl0 != 0.f || bl1 != 0.f);
    const bool fastp = act && (cnt <= 8);       // mixed-column single pass
    const bool slowp = act && (cnt > 8);
    const bool g1    = act && (cnt > 16);

    // pre-R: consumer-row Bh preloads (reads only)
    int ci0 = 64, ci1 = 64, cim = 64;
    const int eh = ml >> 3;                     // fast-path elem per column
    f16x8 Bm0={}, Bm1={};
    f16x8 Bh0e0={}, Bh1e0={}, Bh0e1={}, Bh1e1={};
    f16x8 Ch0e0={}, Ch1e0={}, Ch0e1={}, Ch1e1={};
    if (fastp){
      const int sl = ml & 7;
      cim = (sl < cnt) ? (int)sConsL[t][sl] : 64;
      Bm0 = bc16(sH4[eh][cim][q]);
      Bm1 = bc16(sH4[eh][cim][4+q]);
    } else if (slowp){
      ci0 = (ml < cnt) ? (int)sConsL[t][ml] : 64;
      Bh0e0 = bc16(sH4[0][ci0][q]); Bh1e0 = bc16(sH4[0][ci0][4+q]);
      Bh0e1 = bc16(sH4[1][ci0][q]); Bh1e1 = bc16(sH4[1][ci0][4+q]);
      if (g1){
        ci1 = (16 + ml < cnt) ? (int)sConsL[t][16 + ml] : 64;
        Ch0e0 = bc16(sH4[0][ci1][q]); Ch1e0 = bc16(sH4[0][ci1][4+q]);
        Ch0e1 = bc16(sH4[1][ci1][q]); Ch1e1 = bc16(sH4[1][ci1][4+q]);
      }
    }

    // phase 1 matvec, packed: cols 0-3 elem0, 4-7 elem1 (e = (ml>>2)&1).
    // B per column = h_t of that elem; D[row=16w+4q+reg][ml] = Wch@h_e.
    {
      const int em = (ml >> 2) & 1;
      const f16x8 Hm0 = bc16(sH4[em][t][q]);
      const f16x8 Hm1 = bc16(sH4[em][t][4+q]);
      f32x4 Rv = {0,0,0,0};
      Rv = mfma16(Ac[0], Hm0, Rv);
      Rv = mfma16(Ac[1], Hm1, Rv);
      const int row = 16*w + 4*q + (ml & 3);
      if (ml < 8 && row < SP){
        const int m3 = ml & 3;
        float vv = Rv[0];
        vv = (m3==1) ? Rv[1] : vv;
        vv = (m3==2) ? Rv[2] : vv;
        vv = (m3==3) ? Rv[3] : vv;
        vv += sZdc[em][t][row];
        if (!bwd) vv = tanh_(vv);
        *(f16*)((char*)&sRhoPad[em][0] + 2*row) = (f16)vv;
        const int slot = bwd ? t : (t - (NN-OO));
        if (slot >= 0 && slot < 8)
          *(f16*)((char*)&sRhoHist[em][slot][0] + 2*row) = (f16)vv;
        rho[((size_t)t*BATCH + bp + em)*SP + row] = vv;   // fire & forget
      }
    }
    __syncthreads();   // R: rho visible; pre-R h reads done before writes

    if (fastp){
      // mixed single pass: per-lane elem eh, consumer cim
      const f16x8 Brm0 = bc16(sRhoPad[eh][q]);
      const f16x8 Brm1 = bc16(sRhoPad[eh][4+q]);
      f32x4 Gn={0,0,0,0};
      Gn = mfma16(Ani[0], Brm0, Gn); Gn = mfma16(Ani[1], Brm1, Gn);
      f32x4 Dr={0,0,0,0}, Dz={0,0,0,0}, Dn={0,0,0,0};
      Dr = mfma16(Ar[2], Brm0, Dr); Dr = mfma16(Ar[3], Brm1, Dr);
      Dr = mfma16(Ar[0], Bm0,  Dr); Dr = mfma16(Ar[1], Bm1,  Dr);
      Dz = mfma16(Az[2], Brm0, Dz); Dz = mfma16(Az[3], Brm1, Dz);
      Dz = mfma16(Az[0], Bm0,  Dz); Dz = mfma16(Az[1], Bm1,  Dz);
      Dn = mfma16(Anh[0], Bm0, Dn); Dn = mfma16(Anh[1], Bm1, Dn);
      gates(Dr, Dz, Dn, Gn, ROWB(eh, cim), (ml & 7) < cnt, eh ? bl1 : bl0);
    } else if (slowp){
      const f16x8 Br0e0 = bc16(sRhoPad[0][q]);
      const f16x8 Br1e0 = bc16(sRhoPad[0][4+q]);
      const f16x8 Br0e1 = bc16(sRhoPad[1][q]);
      const f16x8 Br1e1 = bc16(sRhoPad[1][4+q]);
      // consumer-independent accumulators, interleaved elem0/elem1
      f32x4 Gn0={0,0,0,0}, Gn1={0,0,0,0};
      Gn0 = mfma16(Ani[0], Br0e0, Gn0);  Gn1 = mfma16(Ani[0], Br0e1, Gn1);
      Gn0 = mfma16(Ani[1], Br1e0, Gn0);  Gn1 = mfma16(Ani[1], Br1e1, Gn1);
      f32x4 Pr0={0,0,0,0}, Pr1={0,0,0,0};
      Pr0 = mfma16(Ar[2], Br0e0, Pr0);   Pr1 = mfma16(Ar[2], Br0e1, Pr1);
      Pr0 = mfma16(Ar[3], Br1e0, Pr0);   Pr1 = mfma16(Ar[3], Br1e1, Pr1);
      f32x4 Pz0={0,0,0,0}, Pz1={0,0,0,0};
      Pz0 = mfma16(Az[2], Br0e0, Pz0);   Pz1 = mfma16(Az[2], Br0e1, Pz1);
      Pz0 = mfma16(Az[3], Br1e0, Pz0);   Pz1 = mfma16(Az[3], Br1e1, Pz1);

      { // group 0, both elems interleaved
        f32x4 Dr0=Pr0, Dz0=Pz0, Dn0={0,0,0,0};
        f32x4 Dr1=Pr1, Dz1=Pz1, Dn1={0,0,0,0};
        Dr0 = mfma16(Ar[0], Bh0e0, Dr0);  Dr1 = mfma16(Ar[0], Bh0e1, Dr1);
        Dr0 = mfma16(Ar[1], Bh1e0, Dr0);  Dr1 = mfma16(Ar[1], Bh1e1, Dr1);
        Dz0 = mfma16(Az[0], Bh0e0, Dz0);  Dz1 = mfma16(Az[0], Bh0e1, Dz1);
        Dz0 = mfma16(Az[1], Bh1e0, Dz0);  Dz1 = mfma16(Az[1], Bh1e1, Dz1);
        Dn0 = mfma16(Anh[0], Bh0e0, Dn0); Dn1 = mfma16(Anh[0], Bh0e1, Dn1);
        Dn0 = mfma16(Anh[1], Bh1e0, Dn0); Dn1 = mfma16(Anh[1], Bh1e1, Dn1);
        gates(Dr0, Dz0, Dn0, Gn0, ROWB(0,ci0), ml < cnt, bl0);
        gates(Dr1, Dz1, Dn1, Gn1, ROWB(1,ci0), ml < cnt, bl1);
      }
      if (g1){
        f32x4 Dr0=Pr0, Dz0=Pz0, Dn0={0,0,0,0};
        f32x4 Dr1=Pr1, Dz1=Pz1, Dn1={0,0,0,0};
        Dr0 = mfma16(Ar[0], Ch0e0, Dr0);  Dr1 = mfma16(Ar[0], Ch0e1, Dr1);
        Dr0 = mfma16(Ar[1], Ch1e0, Dr0);  Dr1 = mfma16(Ar[1], Ch1e1, Dr1);
        Dz0 = mfma16(Az[0], Ch0e0, Dz0);  Dz1 = mfma16(Az[0], Ch0e1, Dz1);
        Dz0 = mfma16(Az[1], Ch1e0, Dz0);  Dz1 = mfma16(Az[1], Ch1e1, Dz1);
        Dn0 = mfma16(Anh[0], Ch0e0, Dn0); Dn1 = mfma16(Anh[0], Ch0e1, Dn1);
        Dn0 = mfma16(Anh[1], Ch1e0, Dn0); Dn1 = mfma16(Anh[1], Ch1e1, Dn1);
        gates(Dr0, Dz0, Dn0, Gn0, ROWB(0,ci1), 16 + ml < cnt, bl0);
        gates(Dr1, Dz1, Dn1, Gn1, ROWB(1,ci1), 16 + ml < cnt, bl1);
      }
      // groups p>=2 (absent for this input, kept for generality)
      for (int p=2; 16*p < cnt; p++){
        const int idxp = 16*p + ml;
        const int ci = (idxp < cnt) ? (int)sConsL[t][idxp] : 64;
        fullpass(bc16(sH4[0][ci][q]), bc16(sH4[0][ci][4+q]),
                 Br0e0, Br1e0, Gn0, ROWB(0,ci), idxp < cnt, bl0);
        fullpass(bc16(sH4[1][ci][q]), bc16(sH4[1][ci][4+q]),
                 Br0e1, Br1e1, Gn1, ROWB(1,ci), idxp < cnt, bl1);
      }
    }
    __syncthreads();   // C: h writes visible to next step's reads
  }

  // ---- alpha tail: 8 GRU steps on scratch row 64, both elems ----
  for (int s2=0; s2<8; s2++){
    const int i = bwd ? (7 - s2) : (NN - OO + s2);
    const int slot = bwd ? i : (i - (NN-OO));
    const f16x8 Th00 = bc16(sH4[0][64][q]);
    const f16x8 Th01 = bc16(sH4[0][64][4+q]);
    const f16x8 Th10 = bc16(sH4[1][64][q]);
    const f16x8 Th11 = bc16(sH4[1][64][4+q]);
    const f16x8 Tr00 = bc16(sRhoHist[0][slot][q]);
    const f16x8 Tr01 = bc16(sRhoHist[0][slot][4+q]);
    const f16x8 Tr10 = bc16(sRhoHist[1][slot][q]);
    const f16x8 Tr11 = bc16(sRhoHist[1][slot][4+q]);
    f32x4 Gt0={0,0,0,0}, Gt1={0,0,0,0};
    Gt0 = mfma16(Ani[0], Tr00, Gt0);  Gt1 = mfma16(Ani[0], Tr10, Gt1);
    Gt0 = mfma16(Ani[1], Tr01, Gt0);  Gt1 = mfma16(Ani[1], Tr11, Gt1);
    __syncthreads();   // all waves' row-64 reads done before writes
    fullpass(Th00, Th01, Tr00, Tr01, Gt0, ROWB(0,64), ml==0, sHas[0][i]);
    fullpass(Th10, Th11, Tr10, Tr11, Gt1, ROWB(1,64), ml==0, sHas[1][i]);
    __syncthreads();   // writes visible to next tail step
  }
  if (tid < SP){
    alpha[(size_t)(bp  )*SP + tid] = (float)*(const f16*)(ROWB(0,64) + 2*tid);
    alpha[(size_t)(bp+1)*SP + tid] = (float)*(const f16*)(ROWB(1,64) + 2*tid);
  }
  #undef ROWB
}

// One block per batch element: psi + softmaxes, omega, value -> d_out directly.
// r18: float2 LDS reads for psi; softmax 7x32 lanes with shfl_xor.
__global__ __launch_bounds__(256, 1) void head_kernel(float* __restrict__ ws,
                                                      void* __restrict__ outp)
{
  const int b = blockIdx.x;
  const int tid = threadIdx.x;
  const int isbf = (ws[OFF_FLAG] != 0.f);
  const float* hasc   = ws + OFF_HAS;
  const float* WaC    = ws + OFF_WA;
  const float* baC    = ws + OFF_BA;
  const float* WcC    = ws + OFF_WC;
  const float* bcC    = ws + OFF_BC;
  const float* WuC    = ws + OFF_WU;
  const float* buC    = ws + OFF_BU;
  const float* rhoF   = ws + OFF_RHOF;
  const float* rhoB   = ws + OFF_RHOB;
  const float* alphaF = ws + OFF_ALF;
  const float* alphaB = ws + OFF_ALB;

  __shared__ float sF[NN][122];    // 488B stride: float2-aligned
  __shared__ float sAB[120];
  __shared__ float sWu[NR*120];
  __shared__ float sHasR[NN];
  __shared__ float sPsi[NR][NN];
  __shared__ float sOm[NA];

  auto wout = [&](int idx, float v){
    if (isbf) ((u16*)outp)[idx] = f2bf(v);
    else      ((float*)outp)[idx] = v;
  };

  for (int idx=tid; idx<NN*SP; idx+=256){
    int n = idx/SP, s = idx%SP;
    sF[n][s]    = rhoF[((size_t)n*BATCH + b)*SP + s];
    sF[n][60+s] = rhoB[((size_t)n*BATCH + b)*SP + s];
  }
  for (int idx=tid; idx<120; idx+=256)
    sAB[idx] = (idx<60) ? alphaF[(size_t)b*SP + idx] : alphaB[(size_t)b*SP + idx-60];
  for (int idx=tid; idx<NR*120; idx+=256) sWu[idx] = WuC[idx];
  for (int idx=tid; idx<NN; idx+=256) sHasR[idx] = hasc[b*NN + idx];
  __syncthreads();

  for (int idx=tid; idx<NR*NN; idx+=256){
    int r = idx/NN, n = idx%NN;
    const float2* fn = (const float2*)&sF[n][0];
    const float2* wr = (const float2*)&sWu[r*120];
    float acc = buC[r];
    #pragma unroll 6
    for (int s2=0;s2<60;s2++){
      float2 a = fn[s2], c = wr[s2];
      acc += a.x*c.x;
      acc += a.y*c.y;
    }
    sPsi[r][n] = (sHasR[n] != 0.f) ? acc : -60.f;
  }
  if (tid >= 64 && tid < 64+NA){
    int a = tid - 64;
    float acc = baC[a];
    for (int s=0;s<120;s++) acc += sAB[s]*WaC[a*120+s];
    sOm[a] = acc;
  }
  if (tid == 70){
    float acc = bcC[0];
    for (int s=0;s<120;s++) acc += sAB[s]*WcC[s];
    wout(2560 + BATCH*NR*NN + b, acc);                 // value
  }
  __syncthreads();

  if (tid < NR*32){
    const int r = tid >> 5, l = tid & 31;
    float v0 = sPsi[r][l], v1 = sPsi[r][l+32];
    float m = fmaxf(v0, v1);
    #pragma unroll
    for (int o=16;o>0;o>>=1) m = fmaxf(m, __shfl_xor(m, o, 64));
    float e0 = __expf(v0 - m), e1 = __expf(v1 - m);
    float ssum = e0 + e1;
    #pragma unroll
    for (int o=16;o>0;o>>=1) ssum += __shfl_xor(ssum, o, 64);
    float rinv = 1.f/ssum;
    wout(2560 + (size_t)b*NR*NN + r*NN + l,    e0*rinv);   // role_prob
    wout(2560 + (size_t)b*NR*NN + r*NN + l+32, e1*rinv);
  }
  if (tid == 224){   // idle lane in the softmax phase
    float m = -1e30f;
    for (int a=0;a<NA;a++) m = fmaxf(m, sOm[a]);
    float e[NA]; float ssum = 0.f;
    for (int a=0;a<NA;a++){ e[a] = __expf(sOm[a]-m); ssum += e[a]; }
    for (int a=0;a<NA;a++) wout(b*NA + a, e[a]/ssum);  // instr_prob
  }
}

extern "C" void kernel_launch(void* const* d_in, const int* in_sizes, int n_in,
                              void* d_out, int out_size, void* d_ws, size_t ws_size,
                              hipStream_t stream)
{
  const int* adj = (const int*)d_in[3];
  float* ws = (float*)d_ws;

  conv_in<<<(CONV_TOTAL+255)/256, 256, 0, stream>>>(
      d_in[0], d_in[1], d_in[2],
      d_in[4], d_in[5], d_in[6], d_in[7],
      d_in[8], d_in[9], d_in[10], d_in[11],
      d_in[12], d_in[13], d_in[14], d_in[15],
      d_in[16], d_in[17], d_in[18], d_in[19],
      d_in[20], d_in[21], ws);

  dir_kernel<<<512, 256, 0, stream>>>(adj, ws);

  head_kernel<<<512, 256, 0, stream>>>(ws, d_out);
}